// Round 8
// baseline (553.146 us; speedup 1.0000x reference)
//
#include <hip/hip_runtime.h>
#include <hip/hip_bf16.h>

#define DIM 64
#define NC 50
#define TABN 4096
#define TABP (TABN + 2)   // rows 0..4096 = h at p*5/4096, row 4097 = mask row
#define EPB 4096          // edges per block in CSR build
#define NBMAX 512         // max buckets (N <= 65536)

// 64KB LDS tile, XOR-rotated: row n (node), col k (feature); conflict-free both ways
#define BIDX(n,k) (((n)<<6) + ((((k)+(n)))&63))

__device__ __forceinline__ float sp_f(float x){
  // torch Softplus(beta=0.5, threshold=14): 2*log(1+exp(0.5x)), linear when 0.5*x>14
  float e = __expf(0.5f*x);
  float s = 2.0f*__logf(1.0f+e);
  return x > 28.0f ? x : s;
}

__device__ __forceinline__ float rdl(float v, int l){
  return __int_as_float(__builtin_amdgcn_readlane(__float_as_int(v), l));
}

// ---------------- CSR build: two-level LDS counting sort ----------------
// bucket = 128 consecutive dst nodes. No global per-node atomics anywhere.

__global__ __launch_bounds__(256) void bhist_kernel(const int* __restrict__ dst,
                                                    unsigned int* __restrict__ gbcnt,
                                                    unsigned int* __restrict__ flagbits,
                                                    int E, int NB, int FW){
  __shared__ unsigned int cnt[NBMAX];
  int tid = threadIdx.x;
  for (int b=tid; b<NB; b+=256) cnt[b] = 0;
  __syncthreads();
  int e0 = blockIdx.x*EPB, eend = min(e0+EPB, E);
  for (int e=e0+tid; e<eend; e+=256) atomicAdd(&cnt[dst[e]>>7], 1u);
  for (int w = blockIdx.x*256+tid; w < FW; w += gridDim.x*256) flagbits[w] = 0;
  __syncthreads();
  for (int b=tid; b<NB; b+=256) if (cnt[b]) atomicAdd(&gbcnt[b], cnt[b]);
}

__global__ void sel_mark_kernel(const int* __restrict__ sel,
                                unsigned int* __restrict__ flagbits, int K){
  int id = blockIdx.x*256 + threadIdx.x;
  if (id < K){ int e = sel[id]; atomicOr(&flagbits[e>>5], 1u << (e&31)); }
}

__global__ __launch_bounds__(NBMAX) void bscan_kernel(const unsigned int* __restrict__ gbcnt,
                                                      unsigned int* __restrict__ bscan,
                                                      unsigned int* __restrict__ gcursor,
                                                      int* __restrict__ offs,
                                                      int NB, int N, int E){
  __shared__ unsigned int s[NBMAX];
  int tid = threadIdx.x;
  unsigned int v = (tid < NB) ? gbcnt[tid] : 0;
  s[tid] = v;
  __syncthreads();
  for (int off=1; off<NBMAX; off<<=1){
    unsigned int u = (tid >= off) ? s[tid-off] : 0;
    __syncthreads();
    s[tid] += u;
    __syncthreads();
  }
  unsigned int excl = s[tid] - v;
  if (tid < NB){ bscan[tid] = excl; gcursor[tid] = excl; }
  if (tid == NB-1) bscan[NB] = excl + v;
  if (tid == 0) offs[N] = E;
}

__global__ __launch_bounds__(256) void passA_kernel(const int* __restrict__ dst,
                                                    const int* __restrict__ src,
                                                    const float* __restrict__ dist,
                                                    const unsigned int* __restrict__ flagbits,
                                                    unsigned int* __restrict__ gcursor,
                                                    unsigned long long* __restrict__ bbuf,
                                                    int E, int NB){
  __shared__ unsigned int cnt[NBMAX];
  __shared__ unsigned int base[NBMAX];
  int tid = threadIdx.x;
  for (int b=tid; b<NB; b+=256) cnt[b] = 0;
  __syncthreads();
  int e0 = blockIdx.x*EPB, eend = min(e0+EPB, E);
  for (int e=e0+tid; e<eend; e+=256) atomicAdd(&cnt[dst[e]>>7], 1u);
  __syncthreads();
  for (int b=tid; b<NB; b+=256){
    unsigned int c = cnt[b];
    base[b] = c ? atomicAdd(&gcursor[b], c) : 0u;
    cnt[b] = 0;                       // reuse as local cursor
  }
  __syncthreads();
  for (int e=e0+tid; e<eend; e+=256){
    int d = dst[e];
    int b = d >> 7;
    unsigned int loc = atomicAdd(&cnt[b], 1u);
    float t = fminf(dist[e], 5.f) * ((float)TABN/5.0f);
    int idx = (int)(t + 0.5f); if (idx > TABN) idx = TABN;   // nearest grid point
    if ((flagbits[e>>5] >> (e&31)) & 1u) idx = TABN+1;       // mask row
    unsigned int lo = ((unsigned int)src[e] << 16) | (unsigned int)idx; // src<65536
    unsigned int hi = (unsigned int)(d & 127);
    bbuf[base[b] + loc] = ((unsigned long long)hi << 32) | lo;
  }
}

__global__ __launch_bounds__(256) void passB_kernel(const unsigned long long* __restrict__ bbuf,
                                                    const unsigned int* __restrict__ bscan,
                                                    int* __restrict__ offs,
                                                    unsigned int* __restrict__ csr,
                                                    int N){
  __shared__ unsigned int cnt[128];
  __shared__ unsigned int excl[128];
  int b = blockIdx.x, tid = threadIdx.x;
  unsigned int s0 = bscan[b];
  int m = (int)(bscan[b+1] - s0);
  if (tid < 128) cnt[tid] = 0;
  __syncthreads();
  for (int i=tid; i<m; i+=256)
    atomicAdd(&cnt[(unsigned int)(bbuf[s0+i] >> 32)], 1u);
  __syncthreads();
  if (tid < 128) excl[tid] = cnt[tid];
  __syncthreads();
  for (int off=1; off<128; off<<=1){
    unsigned int v = (tid < 128 && tid >= off) ? excl[tid-off] : 0;
    __syncthreads();
    if (tid < 128) excl[tid] += v;
    __syncthreads();
  }
  int node0 = b << 7;
  if (tid < 128){
    unsigned int ex = excl[tid] - cnt[tid];    // exclusive
    int n = node0 + tid;
    if (n < N) offs[n] = (int)(s0 + ex);
    excl[tid] = ex;
    cnt[tid] = 0;                              // reuse as cursor
  }
  __syncthreads();
  for (int i=tid; i<m; i+=256){
    unsigned long long v = bbuf[s0+i];
    unsigned int hi = (unsigned int)(v >> 32);
    unsigned int loc = atomicAdd(&cnt[hi], 1u);
    csr[s0 + excl[hi] + loc] = (unsigned int)v;
  }
}

// ---------------- prep: weight transposes [j][k] -> [k][j] ----------------

__global__ void prep_transpose_kernel(const float* __restrict__ cf_w2,
                                      const float* __restrict__ nl3_w,
                                      const float* __restrict__ conv_w1,
                                      const float* __restrict__ nl2_w,
                                      const float* __restrict__ et1_w,
                                      const float* __restrict__ nt1_w,
                                      const float* __restrict__ cf_w1,
                                      float* __restrict__ w2t,
                                      float* __restrict__ nl3t,
                                      float* __restrict__ cw1t,
                                      float* __restrict__ nl2t,
                                      float* __restrict__ et1t,
                                      float* __restrict__ nt1t,
                                      float* __restrict__ w1t){
  int id = blockIdx.x*256 + threadIdx.x;
  if (id < 3*4096){
    int i = id >> 12, r = id & 4095;
    int k = r >> 6, j = r & 63;
    int s = i*4096 + j*64 + k;
    w2t[id]  = cf_w2[s];
    nl3t[id] = nl3_w[s];
    cw1t[id] = conv_w1[s];
    nl2t[id] = nl2_w[s];
  }
  if (id < 128*64){
    int k = id >> 6, j = id & 63;
    et1t[id] = et1_w[j*128 + k];   // et1_w is [64][128]
  }
  if (id < 64*32){
    int k = id >> 5, j = id & 31;
    nt1t[id] = nt1_w[j*64 + k];    // nt1_w is [32][64]
  }
  if (id < 3*NC*DIM){              // cf_w1 [3][64][50] -> w1t [3][50][64]
    int l = id / (NC*DIM);
    int r = id - l*(NC*DIM);
    int m = r >> 6, k = r & 63;
    w1t[id] = cf_w1[l*DIM*NC + k*NC + m];
  }
}

// ---------------- filter table (bf16, nearest), wave = row, lane = feature ----------------

__global__ __launch_bounds__(256) void table_kernel(const float* __restrict__ edge_mask,
                                                    const float* __restrict__ w1t,   // [3][50][64]
                                                    const float* __restrict__ cf_b1,
                                                    const float* __restrict__ w2t,   // [3][64][64]
                                                    const float* __restrict__ cf_b2,
                                                    __hip_bfloat16* __restrict__ tabb){
  int row = blockIdx.x*4 + (threadIdx.x >> 6);
  if (row >= 3*TABP) return;
  int l = row / TABP, p = row - l*TABP;
  int lane = threadIdx.x & 63;
  float rbfv = 0.f;
  if (lane < NC){
    if (p == TABN+1) rbfv = edge_mask[lane];
    else {
      float d = (float)p * (5.0f/(float)TABN);
      float c = (lane == NC-1) ? 5.0f : (float)((double)lane * (5.0/49.0));
      float df = d - c;
      rbfv = __expf((float)(-1.0/(5.0/49.0)) * df * df);
    }
  }
  const float* W1 = w1t + l*NC*DIM;
  float t = cf_b1[l*DIM + lane];
  #pragma unroll 10
  for (int m=0;m<NC;m++)
    t = fmaf(rdl(rbfv, m), W1[m*64 + lane], t);
  float su = sp_f(t);
  const float* W2 = w2t + l*DIM*DIM;
  float h = cf_b2[l*DIM + lane];
  #pragma unroll 16
  for (int k=0;k<DIM;k++)
    h = fmaf(rdl(su, k), W2[k*64 + lane], h);
  tabb[((size_t)l*TABP + p)*DIM + lane] = __float2bfloat16(h);
}

// ---------------- node-side v2: lane = node, weights via scalar loads ----------------
// Block = 256 threads = 256 nodes. LDS tile B holds the block's 256x64 feature
// panel; thread t's features live in row t (read via BIDX(t,k), conflict-free).
// Weight rows (wave-uniform pointers) come through the scalar pipe (s_load) -> 1
// VALU fma per MAC-row instead of readlane+fma+vector-load.

// node = emb[node_type]; nnb = bf16(node @ W1[0]^T)
__global__ __launch_bounds__(256) void node_init2_kernel(const float* __restrict__ emb,
                                                         const int* __restrict__ node_type,
                                                         const float* __restrict__ cw1t0, // [k][j]
                                                         float* __restrict__ node,
                                                         __hip_bfloat16* __restrict__ nnb, int N){
  __shared__ float B[64*256];
  int tid = threadIdx.x;
  long gbase = (long)blockIdx.x * 16384;
  long lim = (long)N * 64;
  #pragma unroll 8
  for (int c=0;c<64;c++){
    int i = c*256 + tid;
    long gi = gbase + i;
    float v = 0.f;
    if (gi < lim){
      int n = (int)(gi >> 6);
      v = emb[(long)node_type[n]*64 + (i&63)];
      node[gi] = v;                       // coalesced pass-through
    }
    B[BIDX(i>>6, i&63)] = v;
  }
  __syncthreads();
  float o[64];
  #pragma unroll
  for (int j=0;j<64;j++) o[j] = 0.f;
  #pragma unroll 2
  for (int k=0;k<64;k++){
    float xk = B[BIDX(tid, k)];
    const float* wr = cw1t0 + (k<<6);     // wave-uniform -> s_load
    #pragma unroll
    for (int j=0;j<64;j++) o[j] = fmaf(xk, wr[j], o[j]);
  }
  __syncthreads();
  #pragma unroll
  for (int j=0;j<64;j++) B[BIDX(tid, j)] = o[j];   // own row
  __syncthreads();
  #pragma unroll 8
  for (int c=0;c<64;c++){
    int i = c*256 + tid;
    long gi = gbase + i;
    if (gi < lim) nnb[gi] = __float2bfloat16(B[BIDX(i>>6, i&63)]);
  }
}

// node += sp(agg@nl2.T+b)@nl3.T+b; optionally nnb = bf16(node_new @ cw1_next^T)
template<bool PRODUCE_NN>
__global__ __launch_bounds__(256) void node_update2_kernel(float* __restrict__ node,
                                                           const float* __restrict__ agg,
                                                           const float* __restrict__ nl2t,  // [k][j]
                                                           const float* __restrict__ nl2_b,
                                                           const float* __restrict__ nl3t,  // [k][j]
                                                           const float* __restrict__ nl3_b,
                                                           const float* __restrict__ cw1t_next,
                                                           __hip_bfloat16* __restrict__ nnb, int N){
  __shared__ float B[64*256];
  int tid = threadIdx.x;
  long gbase = (long)blockIdx.x * 16384;
  long lim = (long)N * 64;
  // stage agg panel (coalesced -> lane=node rows)
  #pragma unroll 8
  for (int c=0;c<64;c++){
    int i = c*256 + tid;
    long gi = gbase + i;
    float v = (gi < lim) ? agg[gi] : 0.f;
    B[BIDX(i>>6, i&63)] = v;
  }
  __syncthreads();
  // matmul1: u = x @ nl2^T + b
  float u[64];
  #pragma unroll
  for (int j=0;j<64;j++) u[j] = nl2_b[j];
  #pragma unroll 2
  for (int k=0;k<64;k++){
    float xk = B[BIDX(tid, k)];
    const float* wr = nl2t + (k<<6);
    #pragma unroll
    for (int j=0;j<64;j++) u[j] = fmaf(xk, wr[j], u[j]);
  }
  // spu -> own row (avoids runtime-indexed register array; rule #20)
  #pragma unroll
  for (int j=0;j<64;j++) B[BIDX(tid, j)] = sp_f(u[j]);
  // matmul2: cc = spu @ nl3^T + b
  float cc[64];
  #pragma unroll
  for (int j=0;j<64;j++) cc[j] = nl3_b[j];
  #pragma unroll 2
  for (int k=0;k<64;k++){
    float sk = B[BIDX(tid, k)];
    const float* wr = nl3t + (k<<6);
    #pragma unroll
    for (int j=0;j<64;j++) cc[j] = fmaf(sk, wr[j], cc[j]);
  }
  __syncthreads();                       // all rows done before overwrite
  // stage node panel
  #pragma unroll 8
  for (int c=0;c<64;c++){
    int i = c*256 + tid;
    long gi = gbase + i;
    float v = (gi < lim) ? node[gi] : 0.f;
    B[BIDX(i>>6, i&63)] = v;
  }
  __syncthreads();
  // node_new = node + cc -> own row
  #pragma unroll
  for (int j=0;j<64;j++){
    cc[j] += B[BIDX(tid, j)];
    B[BIDX(tid, j)] = cc[j];
  }
  __syncthreads();
  // write node back (coalesced)
  #pragma unroll 8
  for (int c=0;c<64;c++){
    int i = c*256 + tid;
    long gi = gbase + i;
    if (gi < lim) node[gi] = B[BIDX(i>>6, i&63)];
  }
  if (PRODUCE_NN){
    // matmul3: o = node_new @ cw1_next^T (reads own row, unchanged)
    float o[64];
    #pragma unroll
    for (int j=0;j<64;j++) o[j] = 0.f;
    #pragma unroll 2
    for (int k=0;k<64;k++){
      float nk = B[BIDX(tid, k)];
      const float* wr = cw1t_next + (k<<6);
      #pragma unroll
      for (int j=0;j<64;j++) o[j] = fmaf(nk, wr[j], o[j]);
    }
    __syncthreads();                     // write-back readers done
    #pragma unroll
    for (int j=0;j<64;j++) B[BIDX(tid, j)] = o[j];
    __syncthreads();
    #pragma unroll 8
    for (int c=0;c<64;c++){
      int i = c*256 + tid;
      long gi = gbase + i;
      if (gi < lim) nnb[gi] = __float2bfloat16(B[BIDX(i>>6, i&63)]);
    }
  }
}

// gather-aggregate: wave = 1 dst node, lane = feature; 4B csr, bf16 table + new_node
__global__ __launch_bounds__(256) void agg_kernel(const unsigned int* __restrict__ csr,
                                                  const int* __restrict__ offs,
                                                  const unsigned short* __restrict__ tab,  // [TABP][64] bf16
                                                  const unsigned short* __restrict__ nnb,  // bf16 bits
                                                  float* __restrict__ agg, int N){
  int n = blockIdx.x*4 + (threadIdx.x >> 6);
  int lane = threadIdx.x & 63;
  if (n >= N) return;
  int beg = offs[n], end = offs[n+1];
  float acc = 0.f;
  for (int c = beg; c < end; c += 64){
    int m = end - c; if (m > 64) m = 64;
    unsigned int pkv = csr[c + (lane < m ? lane : 0)];   // coalesced edge-list load
    int q = 0;
    for (; q + 8 <= m; q += 8){
      #pragma unroll
      for (int u=0; u<8; u++){
        unsigned int p = (unsigned int)__builtin_amdgcn_readlane((int)pkv, q+u); // SGPR
        int idx = p & 0xFFFF, s = p >> 16;
        float a  = __uint_as_float(((unsigned int)tab[idx*64 + lane]) << 16);
        float nn = __uint_as_float(((unsigned int)nnb[(long)s*64 + lane]) << 16);
        acc = fmaf(nn, a, acc);
      }
    }
    for (; q < m; q++){
      unsigned int p = (unsigned int)__builtin_amdgcn_readlane((int)pkv, q);
      int idx = p & 0xFFFF, s = p >> 16;
      float a  = __uint_as_float(((unsigned int)tab[idx*64 + lane]) << 16);
      float nn = __uint_as_float(((unsigned int)nnb[(long)s*64 + lane]) << 16);
      acc = fmaf(nn, a, acc);
    }
  }
  agg[(long)n*64 + lane] = acc;
}

// ---------------- heads ----------------

__global__ __launch_bounds__(256) void node_head_kernel(const float* __restrict__ node,
                                                        const int* __restrict__ nidx,
                                                        const float* __restrict__ nt1t,  // [64][32]
                                                        const float* __restrict__ nt1_b,
                                                        const float* __restrict__ nt2_w, // [3][32]
                                                        const float* __restrict__ nt2_b,
                                                        float* __restrict__ out, int NSEL){
  int r = __builtin_amdgcn_readfirstlane(blockIdx.x*4 + (threadIdx.x>>6));
  int lane = threadIdx.x & 63;
  if (r >= NSEL) return;
  long n = nidx[r];
  const float* x = node + n*64;                    // uniform -> s_loads
  float u = 0.f;
  if (lane < 32){
    u = nt1_b[lane];
    #pragma unroll
    for (int k=0;k<DIM;k++) u += x[k]*nt1t[k*32 + lane];
  }
  #pragma unroll
  for (int q=0;q<3;q++){
    float v = (lane < 32) ? u*nt2_w[q*32 + lane] : 0.f;
    #pragma unroll
    for (int o=32;o>=1;o>>=1) v += __shfl_xor(v, o);
    if (lane == 0) out[(long)r*3 + q] = nt2_b[q] + v;
  }
}

__global__ __launch_bounds__(256) void edge_head_kernel(const float* __restrict__ node,
                                                        const int* __restrict__ sidx,
                                                        const int* __restrict__ tidx,
                                                        const float* __restrict__ et1t, // [128][64]
                                                        const float* __restrict__ et1_b,
                                                        const float* __restrict__ et2_w,// [5][64]
                                                        const float* __restrict__ et2_b,
                                                        float* __restrict__ out, int ESEL){
  int wid = threadIdx.x >> 6, lane = threadIdx.x & 63;
  int r0 = (blockIdx.x*4 + wid)*4;
  if (r0 >= ESEL) return;
  float xs[4], xt[4], acc[4];
  #pragma unroll
  for (int i=0;i<4;i++){
    int r = r0+i < ESEL ? r0+i : ESEL-1;
    long s = sidx[r], t = tidx[r];
    xs[i] = node[s*64 + lane];
    xt[i] = node[t*64 + lane];
    acc[i] = et1_b[lane];
  }
  #pragma unroll 16
  for (int k=0;k<DIM;k++){
    float w1 = et1t[k*64 + lane];
    float w2 = et1t[(64+k)*64 + lane];
    #pragma unroll
    for (int i=0;i<4;i++){
      acc[i] = fmaf(rdl(xs[i], k), w1, acc[i]);
      acc[i] = fmaf(rdl(xt[i], k), w2, acc[i]);
    }
  }
  #pragma unroll
  for (int i=0;i<4;i++){
    if (r0+i >= ESEL) break;
    #pragma unroll
    for (int q=0;q<5;q++){
      float v = acc[i]*et2_w[q*64 + lane];
      #pragma unroll
      for (int o=32;o>=1;o>>=1) v += __shfl_xor(v, o);
      if (lane == 0) out[(long)(r0+i)*5 + q] = et2_b[q] + v;
    }
  }
}

// ---------------- launch ----------------

extern "C" void kernel_launch(void* const* d_in, const int* in_sizes, int n_in,
                              void* d_out, int out_size, void* d_ws, size_t ws_size,
                              hipStream_t stream){
  const float* emb      = (const float*)d_in[0];
  const float* dist     = (const float*)d_in[1];
  const float* edge_mask= (const float*)d_in[2];
  const float* conv_w1  = (const float*)d_in[3];
  const float* cf_w1    = (const float*)d_in[4];
  const float* cf_b1    = (const float*)d_in[5];
  const float* cf_w2    = (const float*)d_in[6];
  const float* cf_b2    = (const float*)d_in[7];
  const float* nl2_w    = (const float*)d_in[8];
  const float* nl2_b    = (const float*)d_in[9];
  const float* nl3_w    = (const float*)d_in[10];
  const float* nl3_b    = (const float*)d_in[11];
  const float* nt1_w    = (const float*)d_in[12];
  const float* nt1_b    = (const float*)d_in[13];
  const float* nt2_w    = (const float*)d_in[14];
  const float* nt2_b    = (const float*)d_in[15];
  const float* et1_w    = (const float*)d_in[16];
  const float* et1_b    = (const float*)d_in[17];
  const float* et2_w    = (const float*)d_in[18];
  const float* et2_b    = (const float*)d_in[19];
  const int* node_type  = (const int*)d_in[20];
  const int* src        = (const int*)d_in[21];
  const int* dst        = (const int*)d_in[22];
  const int* sel        = (const int*)d_in[23];
  const int* node_index = (const int*)d_in[24];
  const int* source_index = (const int*)d_in[25];
  const int* target_index = (const int*)d_in[26];

  int E    = in_sizes[1];
  int N    = in_sizes[20];
  int K    = in_sizes[23];
  int NSEL = in_sizes[24];
  int ESEL = in_sizes[25];

  int NB  = (N + 127) >> 7;           // buckets of 128 nodes
  int FW  = (E + 31) >> 5;            // flag words
  int nbE = (E + EPB - 1) / EPB;      // CSR-build blocks

  size_t N64 = (size_t)N*64;
  // bbuf (E u64) first for 8B alignment; agg aliases it (lifetimes disjoint)
  unsigned long long* bbuf = (unsigned long long*)d_ws;
  float* agg = (float*)d_ws;
  size_t aggsz = ((size_t)2*E > N64) ? (size_t)2*E : N64;   // float units
  float* p = (float*)d_ws + aggsz;
  float* node     = p; p += N64;
  __hip_bfloat16* nnb = (__hip_bfloat16*)p; p += N64/2;     // bf16 new_node
  float* cw1t     = p; p += 3*4096;
  float* w2t      = p; p += 3*4096;
  float* nl2t     = p; p += 3*4096;
  float* nl3t     = p; p += 3*4096;
  float* et1t     = p; p += 128*64;
  float* nt1t     = p; p += 64*32;
  float* w1t      = p; p += 3*NC*DIM;
  __hip_bfloat16* tabb = (__hip_bfloat16*)p; p += (size_t)3*TABP*DIM/2;
  unsigned int* csr      = (unsigned int*)p; p += E;
  unsigned int* flagbits = (unsigned int*)p; p += FW;
  unsigned int* gbcnt    = (unsigned int*)p; p += NB;
  unsigned int* bscan    = (unsigned int*)p; p += NB+1;
  unsigned int* gcursor  = (unsigned int*)p; p += NB;
  int* offs              = (int*)p; p += N+1;

  // CSR build: two-level LDS counting sort
  hipMemsetAsync(gbcnt, 0, (size_t)NB*sizeof(int), stream);
  bhist_kernel<<<nbE, 256, 0, stream>>>(dst, gbcnt, flagbits, E, NB, FW);
  sel_mark_kernel<<<(K+255)/256, 256, 0, stream>>>(sel, flagbits, K);
  prep_transpose_kernel<<<48, 256, 0, stream>>>(cf_w2, nl3_w, conv_w1, nl2_w, et1_w, nt1_w,
                                                cf_w1, w2t, nl3t, cw1t, nl2t, et1t, nt1t, w1t);
  bscan_kernel<<<1, NBMAX, 0, stream>>>(gbcnt, bscan, gcursor, offs, NB, N, E);
  passA_kernel<<<nbE, 256, 0, stream>>>(dst, src, dist, flagbits, gcursor, bbuf, E, NB);
  passB_kernel<<<NB, 256, 0, stream>>>(bbuf, bscan, offs, csr, N);
  // filter tables (3 layers, wave=row, nearest-neighbor bf16)
  table_kernel<<<(3*TABP+3)/4, 256, 0, stream>>>(edge_mask, w1t, cf_b1, w2t, cf_b2, tabb);

  int nbP  = (N+255)/256;  // node-panel blocks (256 nodes/block)
  int nb_agg = (N+3)/4;    // 4 waves/block x 1 node/wave
  node_init2_kernel<<<nbP, 256, 0, stream>>>(emb, node_type, cw1t, node, nnb, N);
  for (int l=0;l<3;l++){
    agg_kernel<<<nb_agg, 256, 0, stream>>>(csr, offs,
        (const unsigned short*)(tabb + (size_t)l*TABP*DIM),
        (const unsigned short*)nnb, agg, N);
    if (l < 2)
      node_update2_kernel<true><<<nbP, 256, 0, stream>>>(node, agg, nl2t + l*4096, nl2_b + l*64,
          nl3t + l*4096, nl3_b + l*64, cw1t + (l+1)*4096, nnb, N);
    else
      node_update2_kernel<false><<<nbP, 256, 0, stream>>>(node, agg, nl2t + l*4096, nl2_b + l*64,
          nl3t + l*4096, nl3_b + l*64, nullptr, nullptr, N);
  }

  node_head_kernel<<<(NSEL+3)/4, 256, 0, stream>>>(node, node_index,
      nt1t, nt1_b, nt2_w, nt2_b, (float*)d_out, NSEL);
  edge_head_kernel<<<(ESEL+15)/16, 256, 0, stream>>>(node, source_index, target_index,
      et1t, et1_b, et2_w, et2_b, (float*)d_out + (size_t)NSEL*3, ESEL);
}

// Round 9
// 382.739 us; speedup vs baseline: 1.4452x; 1.4452x over previous
//
#include <hip/hip_runtime.h>
#include <hip/hip_bf16.h>

#define DIM 64
#define NC 50
#define TABN 4096
#define TABP (TABN + 2)   // rows 0..4096 = h at p*5/4096, row 4097 = mask row
#define EPB 4096          // edges per block in CSR build
#define NBMAX 512         // max buckets (N <= 65536)

__device__ __forceinline__ float sp_f(float x){
  // torch Softplus(beta=0.5, threshold=14): 2*log(1+exp(0.5x)), linear when 0.5*x>14
  float e = __expf(0.5f*x);
  float s = 2.0f*__logf(1.0f+e);
  return x > 28.0f ? x : s;
}

__device__ __forceinline__ float rdl(float v, int l){
  return __int_as_float(__builtin_amdgcn_readlane(__float_as_int(v), l));
}

// ---------------- CSR build: two-level LDS counting sort ----------------
// bucket = 128 consecutive dst nodes. No global per-node atomics anywhere.

__global__ __launch_bounds__(256) void bhist_kernel(const int* __restrict__ dst,
                                                    unsigned int* __restrict__ gbcnt,
                                                    unsigned int* __restrict__ flagbits,
                                                    int E, int NB, int FW){
  __shared__ unsigned int cnt[NBMAX];
  int tid = threadIdx.x;
  for (int b=tid; b<NB; b+=256) cnt[b] = 0;
  __syncthreads();
  int e0 = blockIdx.x*EPB, eend = min(e0+EPB, E);
  for (int e=e0+tid; e<eend; e+=256) atomicAdd(&cnt[dst[e]>>7], 1u);
  for (int w = blockIdx.x*256+tid; w < FW; w += gridDim.x*256) flagbits[w] = 0;
  __syncthreads();
  for (int b=tid; b<NB; b+=256) if (cnt[b]) atomicAdd(&gbcnt[b], cnt[b]);
}

__global__ void sel_mark_kernel(const int* __restrict__ sel,
                                unsigned int* __restrict__ flagbits, int K){
  int id = blockIdx.x*256 + threadIdx.x;
  if (id < K){ int e = sel[id]; atomicOr(&flagbits[e>>5], 1u << (e&31)); }
}

__global__ __launch_bounds__(NBMAX) void bscan_kernel(const unsigned int* __restrict__ gbcnt,
                                                      unsigned int* __restrict__ bscan,
                                                      unsigned int* __restrict__ gcursor,
                                                      int* __restrict__ offs,
                                                      int NB, int N, int E){
  __shared__ unsigned int s[NBMAX];
  int tid = threadIdx.x;
  unsigned int v = (tid < NB) ? gbcnt[tid] : 0;
  s[tid] = v;
  __syncthreads();
  for (int off=1; off<NBMAX; off<<=1){
    unsigned int u = (tid >= off) ? s[tid-off] : 0;
    __syncthreads();
    s[tid] += u;
    __syncthreads();
  }
  unsigned int excl = s[tid] - v;
  if (tid < NB){ bscan[tid] = excl; gcursor[tid] = excl; }
  if (tid == NB-1) bscan[NB] = excl + v;
  if (tid == 0) offs[N] = E;
}

__global__ __launch_bounds__(256) void passA_kernel(const int* __restrict__ dst,
                                                    const int* __restrict__ src,
                                                    const float* __restrict__ dist,
                                                    const unsigned int* __restrict__ flagbits,
                                                    unsigned int* __restrict__ gcursor,
                                                    unsigned long long* __restrict__ bbuf,
                                                    int E, int NB){
  __shared__ unsigned int cnt[NBMAX];
  __shared__ unsigned int base[NBMAX];
  int tid = threadIdx.x;
  for (int b=tid; b<NB; b+=256) cnt[b] = 0;
  __syncthreads();
  int e0 = blockIdx.x*EPB, eend = min(e0+EPB, E);
  for (int e=e0+tid; e<eend; e+=256) atomicAdd(&cnt[dst[e]>>7], 1u);
  __syncthreads();
  for (int b=tid; b<NB; b+=256){
    unsigned int c = cnt[b];
    base[b] = c ? atomicAdd(&gcursor[b], c) : 0u;
    cnt[b] = 0;                       // reuse as local cursor
  }
  __syncthreads();
  for (int e=e0+tid; e<eend; e+=256){
    int d = dst[e];
    int b = d >> 7;
    unsigned int loc = atomicAdd(&cnt[b], 1u);
    float t = fminf(dist[e], 5.f) * ((float)TABN/5.0f);
    int idx = (int)(t + 0.5f); if (idx > TABN) idx = TABN;   // nearest grid point
    if ((flagbits[e>>5] >> (e&31)) & 1u) idx = TABN+1;       // mask row
    unsigned int lo = ((unsigned int)src[e] << 16) | (unsigned int)idx; // src<65536
    unsigned int hi = (unsigned int)(d & 127);
    bbuf[base[b] + loc] = ((unsigned long long)hi << 32) | lo;
  }
}

__global__ __launch_bounds__(256) void passB_kernel(const unsigned long long* __restrict__ bbuf,
                                                    const unsigned int* __restrict__ bscan,
                                                    int* __restrict__ offs,
                                                    unsigned int* __restrict__ csr,
                                                    int N){
  __shared__ unsigned int cnt[128];
  __shared__ unsigned int excl[128];
  int b = blockIdx.x, tid = threadIdx.x;
  unsigned int s0 = bscan[b];
  int m = (int)(bscan[b+1] - s0);
  if (tid < 128) cnt[tid] = 0;
  __syncthreads();
  for (int i=tid; i<m; i+=256)
    atomicAdd(&cnt[(unsigned int)(bbuf[s0+i] >> 32)], 1u);
  __syncthreads();
  if (tid < 128) excl[tid] = cnt[tid];
  __syncthreads();
  for (int off=1; off<128; off<<=1){
    unsigned int v = (tid < 128 && tid >= off) ? excl[tid-off] : 0;
    __syncthreads();
    if (tid < 128) excl[tid] += v;
    __syncthreads();
  }
  int node0 = b << 7;
  if (tid < 128){
    unsigned int ex = excl[tid] - cnt[tid];    // exclusive
    int n = node0 + tid;
    if (n < N) offs[n] = (int)(s0 + ex);
    excl[tid] = ex;
    cnt[tid] = 0;                              // reuse as cursor
  }
  __syncthreads();
  for (int i=tid; i<m; i+=256){
    unsigned long long v = bbuf[s0+i];
    unsigned int hi = (unsigned int)(v >> 32);
    unsigned int loc = atomicAdd(&cnt[hi], 1u);
    csr[s0 + excl[hi] + loc] = (unsigned int)v;
  }
}

// ---------------- prep: weight transposes (table + heads only) ----------------

__global__ void prep_transpose_kernel(const float* __restrict__ cf_w2,
                                      const float* __restrict__ et1_w,
                                      const float* __restrict__ nt1_w,
                                      const float* __restrict__ cf_w1,
                                      float* __restrict__ w2t,
                                      float* __restrict__ et1t,
                                      float* __restrict__ nt1t,
                                      float* __restrict__ w1t){
  int id = blockIdx.x*256 + threadIdx.x;
  if (id < 3*4096){
    int i = id >> 12, r = id & 4095;
    int k = r >> 6, j = r & 63;
    w2t[id]  = cf_w2[i*4096 + j*64 + k];
  }
  if (id < 128*64){
    int k = id >> 6, j = id & 63;
    et1t[id] = et1_w[j*128 + k];   // et1_w is [64][128]
  }
  if (id < 64*32){
    int k = id >> 5, j = id & 31;
    nt1t[id] = nt1_w[j*64 + k];    // nt1_w is [32][64]
  }
  if (id < 3*NC*DIM){              // cf_w1 [3][64][50] -> w1t [3][50][64]
    int l = id / (NC*DIM);
    int r = id - l*(NC*DIM);
    int m = r >> 6, k = r & 63;
    w1t[id] = cf_w1[l*DIM*NC + k*NC + m];
  }
}

// ---------------- filter table (bf16, nearest), wave = row, lane = feature ----------------

__global__ __launch_bounds__(256) void table_kernel(const float* __restrict__ edge_mask,
                                                    const float* __restrict__ w1t,   // [3][50][64]
                                                    const float* __restrict__ cf_b1,
                                                    const float* __restrict__ w2t,   // [3][64][64]
                                                    const float* __restrict__ cf_b2,
                                                    __hip_bfloat16* __restrict__ tabb){
  int row = blockIdx.x*4 + (threadIdx.x >> 6);
  if (row >= 3*TABP) return;
  int l = row / TABP, p = row - l*TABP;
  int lane = threadIdx.x & 63;
  float rbfv = 0.f;
  if (lane < NC){
    if (p == TABN+1) rbfv = edge_mask[lane];
    else {
      float d = (float)p * (5.0f/(float)TABN);
      float c = (lane == NC-1) ? 5.0f : (float)((double)lane * (5.0/49.0));
      float df = d - c;
      rbfv = __expf((float)(-1.0/(5.0/49.0)) * df * df);
    }
  }
  const float* W1 = w1t + l*NC*DIM;
  float t = cf_b1[l*DIM + lane];
  #pragma unroll 10
  for (int m=0;m<NC;m++)
    t = fmaf(rdl(rbfv, m), W1[m*64 + lane], t);
  float su = sp_f(t);
  const float* W2 = w2t + l*DIM*DIM;
  float h = cf_b2[l*DIM + lane];
  #pragma unroll 16
  for (int k=0;k<DIM;k++)
    h = fmaf(rdl(su, k), W2[k*64 + lane], h);
  tabb[((size_t)l*TABP + p)*DIM + lane] = __float2bfloat16(h);
}

// ---------------- node-side v3: lane = output feature, weights in registers ----------------
// Block = 64 nodes, 4 waves; wave w owns nodes [16w,16w+16). Each lane holds its
// output row W[lane][0..63] in 64 statically-indexed VGPRs; activations are
// broadcast-read from a 16KB LDS panel (ds_read_b128, same addr all lanes -> no
// conflict, LGKM pipe overlaps VALU). 1 VALU fma per MAC. The 3-matmul chain is
// wave-local (own panel rows only) -> single __syncthreads after staging.

#define LOADW(wr) \
  float w[64]; \
  { _Pragma("unroll") \
    for (int q=0;q<16;q++){ float4 v = *(const float4*)((wr) + 4*q); \
      w[4*q]=v.x; w[4*q+1]=v.y; w[4*q+2]=v.z; w[4*q+3]=v.w; } }

#define MM_ROW(xr, acc) \
  float acc; \
  { float a0=0.f,a1=0.f,a2=0.f,a3=0.f; \
    _Pragma("unroll") \
    for (int q=0;q<16;q++){ \
      float4 xv = *(const float4*)((xr) + 4*q); \
      a0 = fmaf(xv.x, w[4*q],   a0); \
      a1 = fmaf(xv.y, w[4*q+1], a1); \
      a2 = fmaf(xv.z, w[4*q+2], a2); \
      a3 = fmaf(xv.w, w[4*q+3], a3); \
    } \
    acc = (a0+a1)+(a2+a3); }

// node = emb[node_type]; nnb = bf16(node @ conv_w1[0]^T)
__global__ __launch_bounds__(256) void node_init3_kernel(const float* __restrict__ emb,
                                                         const int* __restrict__ node_type,
                                                         const float* __restrict__ cw1_0, // [j][k]
                                                         float* __restrict__ node,
                                                         __hip_bfloat16* __restrict__ nnb, int N){
  __shared__ float X[4096];
  __shared__ int types[64];
  int tid = threadIdx.x;
  int wv = tid >> 6, lane = tid & 63;
  int n0 = blockIdx.x*64;
  if (tid < 64) types[tid] = (n0+tid < N) ? node_type[n0+tid] : 0;
  __syncthreads();
  #pragma unroll
  for (int q=0;q<16;q++){
    int i = q*256 + tid;
    int n = i >> 6, k = i & 63;
    float v = emb[(long)types[n]*64 + k];
    X[i] = v;
    if (n0 + n < N) node[(long)n0*64 + i] = v;
  }
  __syncthreads();
  LOADW(cw1_0 + lane*64)
  for (int t=0;t<16;t++){
    int n = wv*16 + t;
    MM_ROW(X + n*64, acc)
    if (n0+n < N) nnb[(long)(n0+n)*64 + lane] = __float2bfloat16(acc);
  }
}

// node += sp(agg@nl2^T+b2)@nl3^T+b3; optionally nnb = bf16(node_new @ cw1_next^T)
template<bool PRODUCE_NN>
__global__ __launch_bounds__(256) void node_update3_kernel(float* __restrict__ node,
                                                           const float* __restrict__ agg,
                                                           const float* __restrict__ nl2_w, // [j][k]
                                                           const float* __restrict__ nl2_b,
                                                           const float* __restrict__ nl3_w, // [j][k]
                                                           const float* __restrict__ nl3_b,
                                                           const float* __restrict__ cw1_next, // [j][k]
                                                           __hip_bfloat16* __restrict__ nnb, int N){
  __shared__ float X[4096];   // agg panel, later node_new panel (own rows only)
  __shared__ float S[4096];   // softplus panel
  int tid = threadIdx.x;
  int wv = tid >> 6, lane = tid & 63;
  int n0 = blockIdx.x*64;
  long lim = ((long)N - n0) * 64;
  const float* ap = agg + (long)n0*64;
  #pragma unroll
  for (int q=0;q<16;q++){
    int i = q*256 + tid;
    X[i] = (i < lim) ? ap[i] : 0.f;
  }
  __syncthreads();
  // phase 1: S = sp(X @ nl2^T + b2)
  {
    LOADW(nl2_w + lane*64)
    float b = nl2_b[lane];
    for (int t=0;t<16;t++){
      int n = wv*16 + t;
      MM_ROW(X + n*64, acc)
      S[n*64 + lane] = sp_f(acc + b);
    }
  }
  // phase 2: node_new = node + S @ nl3^T + b3   (wave-local rows; no sync needed)
  {
    LOADW(nl3_w + lane*64)
    float b = nl3_b[lane];
    for (int t=0;t<16;t++){
      int n = wv*16 + t;
      MM_ROW(S + n*64, acc)
      float nv = 0.f;
      long gi = (long)(n0+n)*64 + lane;
      if (n0+n < N){
        nv = node[gi] + acc + b;
        node[gi] = nv;
      }
      X[n*64 + lane] = nv;     // own row: becomes node_new panel
    }
  }
  if (PRODUCE_NN){
    LOADW(cw1_next + lane*64)
    for (int t=0;t<16;t++){
      int n = wv*16 + t;
      MM_ROW(X + n*64, acc)
      if (n0+n < N) nnb[(long)(n0+n)*64 + lane] = __float2bfloat16(acc);
    }
  }
}

// gather-aggregate: wave = 1 dst node, lane = feature; 4B csr, bf16 table + new_node
__global__ __launch_bounds__(256) void agg_kernel(const unsigned int* __restrict__ csr,
                                                  const int* __restrict__ offs,
                                                  const unsigned short* __restrict__ tab,  // [TABP][64] bf16
                                                  const unsigned short* __restrict__ nnb,  // bf16 bits
                                                  float* __restrict__ agg, int N){
  int n = blockIdx.x*4 + (threadIdx.x >> 6);
  int lane = threadIdx.x & 63;
  if (n >= N) return;
  int beg = offs[n], end = offs[n+1];
  float acc = 0.f;
  for (int c = beg; c < end; c += 64){
    int m = end - c; if (m > 64) m = 64;
    unsigned int pkv = csr[c + (lane < m ? lane : 0)];   // coalesced edge-list load
    int q = 0;
    for (; q + 8 <= m; q += 8){
      #pragma unroll
      for (int u=0; u<8; u++){
        unsigned int p = (unsigned int)__builtin_amdgcn_readlane((int)pkv, q+u); // SGPR
        int idx = p & 0xFFFF, s = p >> 16;
        float a  = __uint_as_float(((unsigned int)tab[idx*64 + lane]) << 16);
        float nn = __uint_as_float(((unsigned int)nnb[(long)s*64 + lane]) << 16);
        acc = fmaf(nn, a, acc);
      }
    }
    for (; q < m; q++){
      unsigned int p = (unsigned int)__builtin_amdgcn_readlane((int)pkv, q);
      int idx = p & 0xFFFF, s = p >> 16;
      float a  = __uint_as_float(((unsigned int)tab[idx*64 + lane]) << 16);
      float nn = __uint_as_float(((unsigned int)nnb[(long)s*64 + lane]) << 16);
      acc = fmaf(nn, a, acc);
    }
  }
  agg[(long)n*64 + lane] = acc;
}

// ---------------- heads ----------------

__global__ __launch_bounds__(256) void node_head_kernel(const float* __restrict__ node,
                                                        const int* __restrict__ nidx,
                                                        const float* __restrict__ nt1t,  // [64][32]
                                                        const float* __restrict__ nt1_b,
                                                        const float* __restrict__ nt2_w, // [3][32]
                                                        const float* __restrict__ nt2_b,
                                                        float* __restrict__ out, int NSEL){
  int r = __builtin_amdgcn_readfirstlane(blockIdx.x*4 + (threadIdx.x>>6));
  int lane = threadIdx.x & 63;
  if (r >= NSEL) return;
  long n = nidx[r];
  const float* x = node + n*64;                    // uniform -> s_loads
  float u = 0.f;
  if (lane < 32){
    u = nt1_b[lane];
    #pragma unroll
    for (int k=0;k<DIM;k++) u += x[k]*nt1t[k*32 + lane];
  }
  #pragma unroll
  for (int q=0;q<3;q++){
    float v = (lane < 32) ? u*nt2_w[q*32 + lane] : 0.f;
    #pragma unroll
    for (int o=32;o>=1;o>>=1) v += __shfl_xor(v, o);
    if (lane == 0) out[(long)r*3 + q] = nt2_b[q] + v;
  }
}

__global__ __launch_bounds__(256) void edge_head_kernel(const float* __restrict__ node,
                                                        const int* __restrict__ sidx,
                                                        const int* __restrict__ tidx,
                                                        const float* __restrict__ et1t, // [128][64]
                                                        const float* __restrict__ et1_b,
                                                        const float* __restrict__ et2_w,// [5][64]
                                                        const float* __restrict__ et2_b,
                                                        float* __restrict__ out, int ESEL){
  int wid = threadIdx.x >> 6, lane = threadIdx.x & 63;
  int r0 = (blockIdx.x*4 + wid)*4;
  if (r0 >= ESEL) return;
  float xs[4], xt[4], acc[4];
  #pragma unroll
  for (int i=0;i<4;i++){
    int r = r0+i < ESEL ? r0+i : ESEL-1;
    long s = sidx[r], t = tidx[r];
    xs[i] = node[s*64 + lane];
    xt[i] = node[t*64 + lane];
    acc[i] = et1_b[lane];
  }
  #pragma unroll 16
  for (int k=0;k<DIM;k++){
    float w1 = et1t[k*64 + lane];
    float w2 = et1t[(64+k)*64 + lane];
    #pragma unroll
    for (int i=0;i<4;i++){
      acc[i] = fmaf(rdl(xs[i], k), w1, acc[i]);
      acc[i] = fmaf(rdl(xt[i], k), w2, acc[i]);
    }
  }
  #pragma unroll
  for (int i=0;i<4;i++){
    if (r0+i >= ESEL) break;
    #pragma unroll
    for (int q=0;q<5;q++){
      float v = acc[i]*et2_w[q*64 + lane];
      #pragma unroll
      for (int o=32;o>=1;o>>=1) v += __shfl_xor(v, o);
      if (lane == 0) out[(long)(r0+i)*5 + q] = et2_b[q] + v;
    }
  }
}

// ---------------- launch ----------------

extern "C" void kernel_launch(void* const* d_in, const int* in_sizes, int n_in,
                              void* d_out, int out_size, void* d_ws, size_t ws_size,
                              hipStream_t stream){
  const float* emb      = (const float*)d_in[0];
  const float* dist     = (const float*)d_in[1];
  const float* edge_mask= (const float*)d_in[2];
  const float* conv_w1  = (const float*)d_in[3];
  const float* cf_w1    = (const float*)d_in[4];
  const float* cf_b1    = (const float*)d_in[5];
  const float* cf_w2    = (const float*)d_in[6];
  const float* cf_b2    = (const float*)d_in[7];
  const float* nl2_w    = (const float*)d_in[8];
  const float* nl2_b    = (const float*)d_in[9];
  const float* nl3_w    = (const float*)d_in[10];
  const float* nl3_b    = (const float*)d_in[11];
  const float* nt1_w    = (const float*)d_in[12];
  const float* nt1_b    = (const float*)d_in[13];
  const float* nt2_w    = (const float*)d_in[14];
  const float* nt2_b    = (const float*)d_in[15];
  const float* et1_w    = (const float*)d_in[16];
  const float* et1_b    = (const float*)d_in[17];
  const float* et2_w    = (const float*)d_in[18];
  const float* et2_b    = (const float*)d_in[19];
  const int* node_type  = (const int*)d_in[20];
  const int* src        = (const int*)d_in[21];
  const int* dst        = (const int*)d_in[22];
  const int* sel        = (const int*)d_in[23];
  const int* node_index = (const int*)d_in[24];
  const int* source_index = (const int*)d_in[25];
  const int* target_index = (const int*)d_in[26];

  int E    = in_sizes[1];
  int N    = in_sizes[20];
  int K    = in_sizes[23];
  int NSEL = in_sizes[24];
  int ESEL = in_sizes[25];

  int NB  = (N + 127) >> 7;           // buckets of 128 nodes
  int FW  = (E + 31) >> 5;            // flag words
  int nbE = (E + EPB - 1) / EPB;      // CSR-build blocks

  size_t N64 = (size_t)N*64;
  // bbuf (E u64) first for 8B alignment; agg aliases it (lifetimes disjoint)
  unsigned long long* bbuf = (unsigned long long*)d_ws;
  float* agg = (float*)d_ws;
  size_t aggsz = ((size_t)2*E > N64) ? (size_t)2*E : N64;   // float units
  float* p = (float*)d_ws + aggsz;
  float* node     = p; p += N64;
  __hip_bfloat16* nnb = (__hip_bfloat16*)p; p += N64/2;     // bf16 new_node
  float* w2t      = p; p += 3*4096;
  float* et1t     = p; p += 128*64;
  float* nt1t     = p; p += 64*32;
  float* w1t      = p; p += 3*NC*DIM;
  __hip_bfloat16* tabb = (__hip_bfloat16*)p; p += (size_t)3*TABP*DIM/2;
  unsigned int* csr      = (unsigned int*)p; p += E;
  unsigned int* flagbits = (unsigned int*)p; p += FW;
  unsigned int* gbcnt    = (unsigned int*)p; p += NB;
  unsigned int* bscan    = (unsigned int*)p; p += NB+1;
  unsigned int* gcursor  = (unsigned int*)p; p += NB;
  int* offs              = (int*)p; p += N+1;

  // CSR build: two-level LDS counting sort
  hipMemsetAsync(gbcnt, 0, (size_t)NB*sizeof(int), stream);
  bhist_kernel<<<nbE, 256, 0, stream>>>(dst, gbcnt, flagbits, E, NB, FW);
  sel_mark_kernel<<<(K+255)/256, 256, 0, stream>>>(sel, flagbits, K);
  prep_transpose_kernel<<<48, 256, 0, stream>>>(cf_w2, et1_w, nt1_w, cf_w1,
                                                w2t, et1t, nt1t, w1t);
  bscan_kernel<<<1, NBMAX, 0, stream>>>(gbcnt, bscan, gcursor, offs, NB, N, E);
  passA_kernel<<<nbE, 256, 0, stream>>>(dst, src, dist, flagbits, gcursor, bbuf, E, NB);
  passB_kernel<<<NB, 256, 0, stream>>>(bbuf, bscan, offs, csr, N);
  // filter tables (3 layers, wave=row, nearest-neighbor bf16)
  table_kernel<<<(3*TABP+3)/4, 256, 0, stream>>>(edge_mask, w1t, cf_b1, w2t, cf_b2, tabb);

  int nbP  = (N+63)/64;    // node-panel blocks (64 nodes/block, 4 waves)
  int nb_agg = (N+3)/4;    // 4 waves/block x 1 node/wave
  node_init3_kernel<<<nbP, 256, 0, stream>>>(emb, node_type, conv_w1, node, nnb, N);
  for (int l=0;l<3;l++){
    agg_kernel<<<nb_agg, 256, 0, stream>>>(csr, offs,
        (const unsigned short*)(tabb + (size_t)l*TABP*DIM),
        (const unsigned short*)nnb, agg, N);
    if (l < 2)
      node_update3_kernel<true><<<nbP, 256, 0, stream>>>(node, agg, nl2_w + l*4096, nl2_b + l*64,
          nl3_w + l*4096, nl3_b + l*64, conv_w1 + (l+1)*4096, nnb, N);
    else
      node_update3_kernel<false><<<nbP, 256, 0, stream>>>(node, agg, nl2_w + l*4096, nl2_b + l*64,
          nl3_w + l*4096, nl3_b + l*64, nullptr, nullptr, N);
  }

  node_head_kernel<<<(NSEL+3)/4, 256, 0, stream>>>(node, node_index,
      nt1t, nt1_b, nt2_w, nt2_b, (float*)d_out, NSEL);
  edge_head_kernel<<<(ESEL+15)/16, 256, 0, stream>>>(node, source_index, target_index,
      et1t, et1_b, et2_w, et2_b, (float*)d_out + (size_t)NSEL*3, ESEL);
}

// Round 10
// 381.487 us; speedup vs baseline: 1.4500x; 1.0033x over previous
//
#include <hip/hip_runtime.h>
#include <hip/hip_bf16.h>

#define DIM 64
#define NC 50
#define TABN 4096
#define TABP (TABN + 2)   // rows 0..4096 = h at p*5/4096, row 4097 = mask row
#define EPB 4096          // edges per block in CSR build
#define NBMAX 512         // max buckets (N <= 65536)

__device__ __forceinline__ float sp_f(float x){
  // torch Softplus(beta=0.5, threshold=14): 2*log(1+exp(0.5x)), linear when 0.5*x>14
  float e = __expf(0.5f*x);
  float s = 2.0f*__logf(1.0f+e);
  return x > 28.0f ? x : s;
}

__device__ __forceinline__ float rdl(float v, int l){
  return __int_as_float(__builtin_amdgcn_readlane(__float_as_int(v), l));
}

// ---------------- CSR build: two-level LDS counting sort ----------------
// bucket = 128 consecutive dst nodes. No global per-node atomics anywhere.

__global__ __launch_bounds__(256) void bhist_kernel(const int* __restrict__ dst,
                                                    unsigned int* __restrict__ gbcnt,
                                                    unsigned int* __restrict__ flagbits,
                                                    int E, int NB, int FW){
  __shared__ unsigned int cnt[NBMAX];
  int tid = threadIdx.x;
  for (int b=tid; b<NB; b+=256) cnt[b] = 0;
  __syncthreads();
  int e0 = blockIdx.x*EPB, eend = min(e0+EPB, E);
  for (int e=e0+tid; e<eend; e+=256) atomicAdd(&cnt[dst[e]>>7], 1u);
  for (int w = blockIdx.x*256+tid; w < FW; w += gridDim.x*256) flagbits[w] = 0;
  __syncthreads();
  for (int b=tid; b<NB; b+=256) if (cnt[b]) atomicAdd(&gbcnt[b], cnt[b]);
}

__global__ void sel_mark_kernel(const int* __restrict__ sel,
                                unsigned int* __restrict__ flagbits, int K){
  int id = blockIdx.x*256 + threadIdx.x;
  if (id < K){ int e = sel[id]; atomicOr(&flagbits[e>>5], 1u << (e&31)); }
}

__global__ __launch_bounds__(NBMAX) void bscan_kernel(const unsigned int* __restrict__ gbcnt,
                                                      unsigned int* __restrict__ bscan,
                                                      unsigned int* __restrict__ gcursor,
                                                      int* __restrict__ offs,
                                                      int NB, int N, int E){
  __shared__ unsigned int s[NBMAX];
  int tid = threadIdx.x;
  unsigned int v = (tid < NB) ? gbcnt[tid] : 0;
  s[tid] = v;
  __syncthreads();
  for (int off=1; off<NBMAX; off<<=1){
    unsigned int u = (tid >= off) ? s[tid-off] : 0;
    __syncthreads();
    s[tid] += u;
    __syncthreads();
  }
  unsigned int excl = s[tid] - v;
  if (tid < NB){ bscan[tid] = excl; gcursor[tid] = excl; }
  if (tid == NB-1) bscan[NB] = excl + v;
  if (tid == 0) offs[N] = E;
}

__global__ __launch_bounds__(256) void passA_kernel(const int* __restrict__ dst,
                                                    const int* __restrict__ src,
                                                    const float* __restrict__ dist,
                                                    const unsigned int* __restrict__ flagbits,
                                                    unsigned int* __restrict__ gcursor,
                                                    unsigned long long* __restrict__ bbuf,
                                                    int E, int NB){
  __shared__ unsigned int cnt[NBMAX];
  __shared__ unsigned int base[NBMAX];
  int tid = threadIdx.x;
  for (int b=tid; b<NB; b+=256) cnt[b] = 0;
  __syncthreads();
  int e0 = blockIdx.x*EPB, eend = min(e0+EPB, E);
  for (int e=e0+tid; e<eend; e+=256) atomicAdd(&cnt[dst[e]>>7], 1u);
  __syncthreads();
  for (int b=tid; b<NB; b+=256){
    unsigned int c = cnt[b];
    base[b] = c ? atomicAdd(&gcursor[b], c) : 0u;
    cnt[b] = 0;                       // reuse as local cursor
  }
  __syncthreads();
  for (int e=e0+tid; e<eend; e+=256){
    int d = dst[e];
    int b = d >> 7;
    unsigned int loc = atomicAdd(&cnt[b], 1u);
    float t = fminf(dist[e], 5.f) * ((float)TABN/5.0f);
    int idx = (int)(t + 0.5f); if (idx > TABN) idx = TABN;   // nearest grid point
    if ((flagbits[e>>5] >> (e&31)) & 1u) idx = TABN+1;       // mask row
    unsigned int lo = ((unsigned int)src[e] << 16) | (unsigned int)idx; // src<65536
    unsigned int hi = (unsigned int)(d & 127);
    bbuf[base[b] + loc] = ((unsigned long long)hi << 32) | lo;
  }
}

__global__ __launch_bounds__(256) void passB_kernel(const unsigned long long* __restrict__ bbuf,
                                                    const unsigned int* __restrict__ bscan,
                                                    int* __restrict__ offs,
                                                    unsigned int* __restrict__ csr,
                                                    int N){
  __shared__ unsigned int cnt[128];
  __shared__ unsigned int excl[128];
  int b = blockIdx.x, tid = threadIdx.x;
  unsigned int s0 = bscan[b];
  int m = (int)(bscan[b+1] - s0);
  if (tid < 128) cnt[tid] = 0;
  __syncthreads();
  for (int i=tid; i<m; i+=256)
    atomicAdd(&cnt[(unsigned int)(bbuf[s0+i] >> 32)], 1u);
  __syncthreads();
  if (tid < 128) excl[tid] = cnt[tid];
  __syncthreads();
  for (int off=1; off<128; off<<=1){
    unsigned int v = (tid < 128 && tid >= off) ? excl[tid-off] : 0;
    __syncthreads();
    if (tid < 128) excl[tid] += v;
    __syncthreads();
  }
  int node0 = b << 7;
  if (tid < 128){
    unsigned int ex = excl[tid] - cnt[tid];    // exclusive
    int n = node0 + tid;
    if (n < N) offs[n] = (int)(s0 + ex);
    excl[tid] = ex;
    cnt[tid] = 0;                              // reuse as cursor
  }
  __syncthreads();
  for (int i=tid; i<m; i+=256){
    unsigned long long v = bbuf[s0+i];
    unsigned int hi = (unsigned int)(v >> 32);
    unsigned int loc = atomicAdd(&cnt[hi], 1u);
    csr[s0 + excl[hi] + loc] = (unsigned int)v;
  }
}

// ---------------- prep: weight transposes (table + heads only) ----------------

__global__ void prep_transpose_kernel(const float* __restrict__ cf_w2,
                                      const float* __restrict__ et1_w,
                                      const float* __restrict__ nt1_w,
                                      const float* __restrict__ cf_w1,
                                      float* __restrict__ w2t,
                                      float* __restrict__ et1t,
                                      float* __restrict__ nt1t,
                                      float* __restrict__ w1t){
  int id = blockIdx.x*256 + threadIdx.x;
  if (id < 3*4096){
    int i = id >> 12, r = id & 4095;
    int k = r >> 6, j = r & 63;
    w2t[id]  = cf_w2[i*4096 + j*64 + k];
  }
  if (id < 128*64){
    int k = id >> 6, j = id & 63;
    et1t[id] = et1_w[j*128 + k];   // et1_w is [64][128]
  }
  if (id < 64*32){
    int k = id >> 5, j = id & 31;
    nt1t[id] = nt1_w[j*64 + k];    // nt1_w is [32][64]
  }
  if (id < 3*NC*DIM){              // cf_w1 [3][64][50] -> w1t [3][50][64]
    int l = id / (NC*DIM);
    int r = id - l*(NC*DIM);
    int m = r >> 6, k = r & 63;
    w1t[id] = cf_w1[l*DIM*NC + k*NC + m];
  }
}

// ---------------- filter table (bf16, nearest), wave = row, lane = feature ----------------

__global__ __launch_bounds__(256) void table_kernel(const float* __restrict__ edge_mask,
                                                    const float* __restrict__ w1t,   // [3][50][64]
                                                    const float* __restrict__ cf_b1,
                                                    const float* __restrict__ w2t,   // [3][64][64]
                                                    const float* __restrict__ cf_b2,
                                                    __hip_bfloat16* __restrict__ tabb){
  int row = blockIdx.x*4 + (threadIdx.x >> 6);
  if (row >= 3*TABP) return;
  int l = row / TABP, p = row - l*TABP;
  int lane = threadIdx.x & 63;
  float rbfv = 0.f;
  if (lane < NC){
    if (p == TABN+1) rbfv = edge_mask[lane];
    else {
      float d = (float)p * (5.0f/(float)TABN);
      float c = (lane == NC-1) ? 5.0f : (float)((double)lane * (5.0/49.0));
      float df = d - c;
      rbfv = __expf((float)(-1.0/(5.0/49.0)) * df * df);
    }
  }
  const float* W1 = w1t + l*NC*DIM;
  float t = cf_b1[l*DIM + lane];
  #pragma unroll 10
  for (int m=0;m<NC;m++)
    t = fmaf(rdl(rbfv, m), W1[m*64 + lane], t);
  float su = sp_f(t);
  const float* W2 = w2t + l*DIM*DIM;
  float h = cf_b2[l*DIM + lane];
  #pragma unroll 16
  for (int k=0;k<DIM;k++)
    h = fmaf(rdl(su, k), W2[k*64 + lane], h);
  tabb[((size_t)l*TABP + p)*DIM + lane] = __float2bfloat16(h);
}

// ---------------- node-side v4: lane = output feature, acc-resident loop order ----
// Block = 64 nodes, 4 waves; wave w owns nodes [16w,16w+16) = its own 16 panel
// rows (wave-local staging -> NO __syncthreads in the matmul chain).
// Loop order q(weight chunk) -> t(node): each weight float4 is loaded exactly
// once per q by construction (16 loads/matmul, can't be rematerialized into the
// hot loop), and the live set is acc[16] + wq + xv ~ 40-70 VGPR.

#define MM16(PANEL, WPTR, ACC) \
  float ACC[16]; \
  { \
    _Pragma("unroll") \
    for (int t0=0;t0<16;t0++) ACC[t0]=0.f; \
    const float* wp_ = (WPTR); \
    _Pragma("unroll 4") \
    for (int q=0;q<16;q++){ \
      float4 wq = *(const float4*)(wp_ + 4*q); \
      _Pragma("unroll") \
      for (int t=0;t<16;t++){ \
        float4 xv = *(const float4*)((PANEL) + t*64 + 4*q); \
        ACC[t] = fmaf(xv.x, wq.x, ACC[t]); \
        ACC[t] = fmaf(xv.y, wq.y, ACC[t]); \
        ACC[t] = fmaf(xv.z, wq.z, ACC[t]); \
        ACC[t] = fmaf(xv.w, wq.w, ACC[t]); \
      } \
    } \
  }

// node = emb[node_type]; nnb = bf16(node @ conv_w1[0]^T)
__global__ __launch_bounds__(256) void node_init4_kernel(const float* __restrict__ emb,
                                                         const int* __restrict__ node_type,
                                                         const float* __restrict__ cw1_0, // [j][k]
                                                         float* __restrict__ node,
                                                         __hip_bfloat16* __restrict__ nnb, int N){
  __shared__ float X[4096];
  __shared__ int types[64];
  int tid = threadIdx.x;
  int wv = tid >> 6, lane = tid & 63;
  int n0 = blockIdx.x*64;
  int nb = n0 + wv*16;
  if (tid < 64) types[tid] = (n0+tid < N) ? node_type[n0+tid] : 0;
  __syncthreads();
  float* xw = X + wv*1024;
  #pragma unroll
  for (int t=0;t<16;t++){
    int n = nb + t;
    float v = emb[(long)types[wv*16+t]*64 + lane];
    xw[t*64 + lane] = v;
    if (n < N) node[(long)n*64 + lane] = v;
  }
  MM16(xw, cw1_0 + lane*64, a0)
  #pragma unroll
  for (int t=0;t<16;t++){
    int n = nb + t;
    if (n < N) nnb[(long)n*64 + lane] = __float2bfloat16(a0[t]);
  }
}

// node += sp(agg@nl2^T+b2)@nl3^T+b3; optionally nnb = bf16(node_new @ cw1_next^T)
template<bool PRODUCE_NN>
__global__ __launch_bounds__(256) void node_update4_kernel(float* __restrict__ node,
                                                           const float* __restrict__ agg,
                                                           const float* __restrict__ nl2_w, // [j][k]
                                                           const float* __restrict__ nl2_b,
                                                           const float* __restrict__ nl3_w, // [j][k]
                                                           const float* __restrict__ nl3_b,
                                                           const float* __restrict__ cw1_next, // [j][k]
                                                           __hip_bfloat16* __restrict__ nnb, int N){
  __shared__ float X[4096];   // agg panel, later node_new panel (wave-local rows)
  __shared__ float S[4096];   // softplus panel (wave-local rows)
  int tid = threadIdx.x;
  int wv = tid >> 6, lane = tid & 63;
  int nb = blockIdx.x*64 + wv*16;
  float* xw = X + wv*1024;
  float* sw = S + wv*1024;
  // stage agg rows (wave-local; no block barrier needed anywhere)
  #pragma unroll
  for (int t=0;t<16;t++){
    int n = nb + t;
    xw[t*64 + lane] = (n < N) ? agg[(long)n*64 + lane] : 0.f;
  }
  // phase 1: S = sp(X @ nl2^T + b2)
  MM16(xw, nl2_w + lane*64, a1)
  float b2 = nl2_b[lane];
  #pragma unroll
  for (int t=0;t<16;t++) sw[t*64 + lane] = sp_f(a1[t] + b2);
  // phase 2: node_new = node + S @ nl3^T + b3
  MM16(sw, nl3_w + lane*64, a2)
  float b3 = nl3_b[lane];
  #pragma unroll
  for (int t=0;t<16;t++){
    int n = nb + t;
    float nv = 0.f;
    if (n < N){
      long gi = (long)n*64 + lane;
      nv = node[gi] + a2[t] + b3;
      node[gi] = nv;
    }
    xw[t*64 + lane] = nv;     // own rows: becomes node_new panel
  }
  if (PRODUCE_NN){
    MM16(xw, cw1_next + lane*64, a3)
    #pragma unroll
    for (int t=0;t<16;t++){
      int n = nb + t;
      if (n < N) nnb[(long)n*64 + lane] = __float2bfloat16(a3[t]);
    }
  }
}

// gather-aggregate: wave = 1 dst node, lane = feature; 4B csr, bf16 table + new_node
__global__ __launch_bounds__(256) void agg_kernel(const unsigned int* __restrict__ csr,
                                                  const int* __restrict__ offs,
                                                  const unsigned short* __restrict__ tab,  // [TABP][64] bf16
                                                  const unsigned short* __restrict__ nnb,  // bf16 bits
                                                  float* __restrict__ agg, int N){
  int n = blockIdx.x*4 + (threadIdx.x >> 6);
  int lane = threadIdx.x & 63;
  if (n >= N) return;
  int beg = offs[n], end = offs[n+1];
  float acc = 0.f;
  for (int c = beg; c < end; c += 64){
    int m = end - c; if (m > 64) m = 64;
    unsigned int pkv = csr[c + (lane < m ? lane : 0)];   // coalesced edge-list load
    int q = 0;
    for (; q + 8 <= m; q += 8){
      #pragma unroll
      for (int u=0; u<8; u++){
        unsigned int p = (unsigned int)__builtin_amdgcn_readlane((int)pkv, q+u); // SGPR
        int idx = p & 0xFFFF, s = p >> 16;
        float a  = __uint_as_float(((unsigned int)tab[idx*64 + lane]) << 16);
        float nn = __uint_as_float(((unsigned int)nnb[(long)s*64 + lane]) << 16);
        acc = fmaf(nn, a, acc);
      }
    }
    for (; q < m; q++){
      unsigned int p = (unsigned int)__builtin_amdgcn_readlane((int)pkv, q);
      int idx = p & 0xFFFF, s = p >> 16;
      float a  = __uint_as_float(((unsigned int)tab[idx*64 + lane]) << 16);
      float nn = __uint_as_float(((unsigned int)nnb[(long)s*64 + lane]) << 16);
      acc = fmaf(nn, a, acc);
    }
  }
  agg[(long)n*64 + lane] = acc;
}

// ---------------- heads ----------------

__global__ __launch_bounds__(256) void node_head_kernel(const float* __restrict__ node,
                                                        const int* __restrict__ nidx,
                                                        const float* __restrict__ nt1t,  // [64][32]
                                                        const float* __restrict__ nt1_b,
                                                        const float* __restrict__ nt2_w, // [3][32]
                                                        const float* __restrict__ nt2_b,
                                                        float* __restrict__ out, int NSEL){
  int r = __builtin_amdgcn_readfirstlane(blockIdx.x*4 + (threadIdx.x>>6));
  int lane = threadIdx.x & 63;
  if (r >= NSEL) return;
  long n = nidx[r];
  const float* x = node + n*64;                    // uniform -> s_loads
  float u = 0.f;
  if (lane < 32){
    u = nt1_b[lane];
    #pragma unroll
    for (int k=0;k<DIM;k++) u += x[k]*nt1t[k*32 + lane];
  }
  #pragma unroll
  for (int q=0;q<3;q++){
    float v = (lane < 32) ? u*nt2_w[q*32 + lane] : 0.f;
    #pragma unroll
    for (int o=32;o>=1;o>>=1) v += __shfl_xor(v, o);
    if (lane == 0) out[(long)r*3 + q] = nt2_b[q] + v;
  }
}

__global__ __launch_bounds__(256) void edge_head_kernel(const float* __restrict__ node,
                                                        const int* __restrict__ sidx,
                                                        const int* __restrict__ tidx,
                                                        const float* __restrict__ et1t, // [128][64]
                                                        const float* __restrict__ et1_b,
                                                        const float* __restrict__ et2_w,// [5][64]
                                                        const float* __restrict__ et2_b,
                                                        float* __restrict__ out, int ESEL){
  int wid = threadIdx.x >> 6, lane = threadIdx.x & 63;
  int r0 = (blockIdx.x*4 + wid)*4;
  if (r0 >= ESEL) return;
  float xs[4], xt[4], acc[4];
  #pragma unroll
  for (int i=0;i<4;i++){
    int r = r0+i < ESEL ? r0+i : ESEL-1;
    long s = sidx[r], t = tidx[r];
    xs[i] = node[s*64 + lane];
    xt[i] = node[t*64 + lane];
    acc[i] = et1_b[lane];
  }
  #pragma unroll 16
  for (int k=0;k<DIM;k++){
    float w1 = et1t[k*64 + lane];
    float w2 = et1t[(64+k)*64 + lane];
    #pragma unroll
    for (int i=0;i<4;i++){
      acc[i] = fmaf(rdl(xs[i], k), w1, acc[i]);
      acc[i] = fmaf(rdl(xt[i], k), w2, acc[i]);
    }
  }
  #pragma unroll
  for (int i=0;i<4;i++){
    if (r0+i >= ESEL) break;
    #pragma unroll
    for (int q=0;q<5;q++){
      float v = acc[i]*et2_w[q*64 + lane];
      #pragma unroll
      for (int o=32;o>=1;o>>=1) v += __shfl_xor(v, o);
      if (lane == 0) out[(long)(r0+i)*5 + q] = et2_b[q] + v;
    }
  }
}

// ---------------- launch ----------------

extern "C" void kernel_launch(void* const* d_in, const int* in_sizes, int n_in,
                              void* d_out, int out_size, void* d_ws, size_t ws_size,
                              hipStream_t stream){
  const float* emb      = (const float*)d_in[0];
  const float* dist     = (const float*)d_in[1];
  const float* edge_mask= (const float*)d_in[2];
  const float* conv_w1  = (const float*)d_in[3];
  const float* cf_w1    = (const float*)d_in[4];
  const float* cf_b1    = (const float*)d_in[5];
  const float* cf_w2    = (const float*)d_in[6];
  const float* cf_b2    = (const float*)d_in[7];
  const float* nl2_w    = (const float*)d_in[8];
  const float* nl2_b    = (const float*)d_in[9];
  const float* nl3_w    = (const float*)d_in[10];
  const float* nl3_b    = (const float*)d_in[11];
  const float* nt1_w    = (const float*)d_in[12];
  const float* nt1_b    = (const float*)d_in[13];
  const float* nt2_w    = (const float*)d_in[14];
  const float* nt2_b    = (const float*)d_in[15];
  const float* et1_w    = (const float*)d_in[16];
  const float* et1_b    = (const float*)d_in[17];
  const float* et2_w    = (const float*)d_in[18];
  const float* et2_b    = (const float*)d_in[19];
  const int* node_type  = (const int*)d_in[20];
  const int* src        = (const int*)d_in[21];
  const int* dst        = (const int*)d_in[22];
  const int* sel        = (const int*)d_in[23];
  const int* node_index = (const int*)d_in[24];
  const int* source_index = (const int*)d_in[25];
  const int* target_index = (const int*)d_in[26];

  int E    = in_sizes[1];
  int N    = in_sizes[20];
  int K    = in_sizes[23];
  int NSEL = in_sizes[24];
  int ESEL = in_sizes[25];

  int NB  = (N + 127) >> 7;           // buckets of 128 nodes
  int FW  = (E + 31) >> 5;            // flag words
  int nbE = (E + EPB - 1) / EPB;      // CSR-build blocks

  size_t N64 = (size_t)N*64;
  // bbuf (E u64) first for 8B alignment; agg aliases it (lifetimes disjoint)
  unsigned long long* bbuf = (unsigned long long*)d_ws;
  float* agg = (float*)d_ws;
  size_t aggsz = ((size_t)2*E > N64) ? (size_t)2*E : N64;   // float units
  float* p = (float*)d_ws + aggsz;
  float* node     = p; p += N64;
  __hip_bfloat16* nnb = (__hip_bfloat16*)p; p += N64/2;     // bf16 new_node
  float* w2t      = p; p += 3*4096;
  float* et1t     = p; p += 128*64;
  float* nt1t     = p; p += 64*32;
  float* w1t      = p; p += 3*NC*DIM;
  __hip_bfloat16* tabb = (__hip_bfloat16*)p; p += (size_t)3*TABP*DIM/2;
  unsigned int* csr      = (unsigned int*)p; p += E;
  unsigned int* flagbits = (unsigned int*)p; p += FW;
  unsigned int* gbcnt    = (unsigned int*)p; p += NB;
  unsigned int* bscan    = (unsigned int*)p; p += NB+1;
  unsigned int* gcursor  = (unsigned int*)p; p += NB;
  int* offs              = (int*)p; p += N+1;

  // CSR build: two-level LDS counting sort
  hipMemsetAsync(gbcnt, 0, (size_t)NB*sizeof(int), stream);
  bhist_kernel<<<nbE, 256, 0, stream>>>(dst, gbcnt, flagbits, E, NB, FW);
  sel_mark_kernel<<<(K+255)/256, 256, 0, stream>>>(sel, flagbits, K);
  prep_transpose_kernel<<<48, 256, 0, stream>>>(cf_w2, et1_w, nt1_w, cf_w1,
                                                w2t, et1t, nt1t, w1t);
  bscan_kernel<<<1, NBMAX, 0, stream>>>(gbcnt, bscan, gcursor, offs, NB, N, E);
  passA_kernel<<<nbE, 256, 0, stream>>>(dst, src, dist, flagbits, gcursor, bbuf, E, NB);
  passB_kernel<<<NB, 256, 0, stream>>>(bbuf, bscan, offs, csr, N);
  // filter tables (3 layers, wave=row, nearest-neighbor bf16)
  table_kernel<<<(3*TABP+3)/4, 256, 0, stream>>>(edge_mask, w1t, cf_b1, w2t, cf_b2, tabb);

  int nbP  = (N+63)/64;    // node-panel blocks (64 nodes/block, 4 waves)
  int nb_agg = (N+3)/4;    // 4 waves/block x 1 node/wave
  node_init4_kernel<<<nbP, 256, 0, stream>>>(emb, node_type, conv_w1, node, nnb, N);
  for (int l=0;l<3;l++){
    agg_kernel<<<nb_agg, 256, 0, stream>>>(csr, offs,
        (const unsigned short*)(tabb + (size_t)l*TABP*DIM),
        (const unsigned short*)nnb, agg, N);
    if (l < 2)
      node_update4_kernel<true><<<nbP, 256, 0, stream>>>(node, agg, nl2_w + l*4096, nl2_b + l*64,
          nl3_w + l*4096, nl3_b + l*64, conv_w1 + (l+1)*4096, nnb, N);
    else
      node_update4_kernel<false><<<nbP, 256, 0, stream>>>(node, agg, nl2_w + l*4096, nl2_b + l*64,
          nl3_w + l*4096, nl3_b + l*64, nullptr, nullptr, N);
  }

  node_head_kernel<<<(NSEL+3)/4, 256, 0, stream>>>(node, node_index,
      nt1t, nt1_b, nt2_w, nt2_b, (float*)d_out, NSEL);
  edge_head_kernel<<<(ESEL+15)/16, 256, 0, stream>>>(node, source_index, target_index,
      et1t, et1_b, et2_w, et2_b, (float*)d_out + (size_t)NSEL*3, ESEL);
}

// Round 11
// 381.354 us; speedup vs baseline: 1.4505x; 1.0003x over previous
//
#include <hip/hip_runtime.h>
#include <hip/hip_bf16.h>

#define DIM 64
#define NC 50
#define TABN 4096
#define TABP (TABN + 2)   // rows 0..4096 = h at p*5/4096, row 4097 = mask row
#define EPB 4096          // edges per block in CSR build
#define NBMAX 512         // max buckets (N <= 65536)

__device__ __forceinline__ float sp_f(float x){
  // torch Softplus(beta=0.5, threshold=14): 2*log(1+exp(0.5x)), linear when 0.5*x>14
  float e = __expf(0.5f*x);
  float s = 2.0f*__logf(1.0f+e);
  return x > 28.0f ? x : s;
}

__device__ __forceinline__ float rdl(float v, int l){
  return __int_as_float(__builtin_amdgcn_readlane(__float_as_int(v), l));
}

// ---------------- CSR build: two-level LDS counting sort ----------------
// bucket = 128 consecutive dst nodes. No global per-node atomics anywhere.

__global__ __launch_bounds__(256) void bhist_kernel(const int* __restrict__ dst,
                                                    unsigned int* __restrict__ gbcnt,
                                                    unsigned int* __restrict__ flagbits,
                                                    int E, int NB, int FW){
  __shared__ unsigned int cnt[NBMAX];
  int tid = threadIdx.x;
  for (int b=tid; b<NB; b+=256) cnt[b] = 0;
  __syncthreads();
  int e0 = blockIdx.x*EPB, eend = min(e0+EPB, E);
  for (int e=e0+tid; e<eend; e+=256) atomicAdd(&cnt[dst[e]>>7], 1u);
  for (int w = blockIdx.x*256+tid; w < FW; w += gridDim.x*256) flagbits[w] = 0;
  __syncthreads();
  for (int b=tid; b<NB; b+=256) if (cnt[b]) atomicAdd(&gbcnt[b], cnt[b]);
}

__global__ void sel_mark_kernel(const int* __restrict__ sel,
                                unsigned int* __restrict__ flagbits, int K){
  int id = blockIdx.x*256 + threadIdx.x;
  if (id < K){ int e = sel[id]; atomicOr(&flagbits[e>>5], 1u << (e&31)); }
}

__global__ __launch_bounds__(NBMAX) void bscan_kernel(const unsigned int* __restrict__ gbcnt,
                                                      unsigned int* __restrict__ bscan,
                                                      unsigned int* __restrict__ gcursor,
                                                      int* __restrict__ offs,
                                                      int NB, int N, int E){
  __shared__ unsigned int s[NBMAX];
  int tid = threadIdx.x;
  unsigned int v = (tid < NB) ? gbcnt[tid] : 0;
  s[tid] = v;
  __syncthreads();
  for (int off=1; off<NBMAX; off<<=1){
    unsigned int u = (tid >= off) ? s[tid-off] : 0;
    __syncthreads();
    s[tid] += u;
    __syncthreads();
  }
  unsigned int excl = s[tid] - v;
  if (tid < NB){ bscan[tid] = excl; gcursor[tid] = excl; }
  if (tid == NB-1) bscan[NB] = excl + v;
  if (tid == 0) offs[N] = E;
}

__global__ __launch_bounds__(256) void passA_kernel(const int* __restrict__ dst,
                                                    const int* __restrict__ src,
                                                    const float* __restrict__ dist,
                                                    const unsigned int* __restrict__ flagbits,
                                                    unsigned int* __restrict__ gcursor,
                                                    unsigned long long* __restrict__ bbuf,
                                                    int E, int NB){
  __shared__ unsigned int cnt[NBMAX];
  __shared__ unsigned int base[NBMAX];
  int tid = threadIdx.x;
  for (int b=tid; b<NB; b+=256) cnt[b] = 0;
  __syncthreads();
  int e0 = blockIdx.x*EPB, eend = min(e0+EPB, E);
  for (int e=e0+tid; e<eend; e+=256) atomicAdd(&cnt[dst[e]>>7], 1u);
  __syncthreads();
  for (int b=tid; b<NB; b+=256){
    unsigned int c = cnt[b];
    base[b] = c ? atomicAdd(&gcursor[b], c) : 0u;
    cnt[b] = 0;                       // reuse as local cursor
  }
  __syncthreads();
  for (int e=e0+tid; e<eend; e+=256){
    int d = dst[e];
    int b = d >> 7;
    unsigned int loc = atomicAdd(&cnt[b], 1u);
    float t = fminf(dist[e], 5.f) * ((float)TABN/5.0f);
    int idx = (int)(t + 0.5f); if (idx > TABN) idx = TABN;   // nearest grid point
    if ((flagbits[e>>5] >> (e&31)) & 1u) idx = TABN+1;       // mask row
    unsigned int lo = ((unsigned int)src[e] << 16) | (unsigned int)idx; // src<65536
    unsigned int hi = (unsigned int)(d & 127);
    bbuf[base[b] + loc] = ((unsigned long long)hi << 32) | lo;
  }
}

__global__ __launch_bounds__(256) void passB_kernel(const unsigned long long* __restrict__ bbuf,
                                                    const unsigned int* __restrict__ bscan,
                                                    int* __restrict__ offs,
                                                    unsigned int* __restrict__ csr,
                                                    int N){
  __shared__ unsigned int cnt[128];
  __shared__ unsigned int excl[128];
  int b = blockIdx.x, tid = threadIdx.x;
  unsigned int s0 = bscan[b];
  int m = (int)(bscan[b+1] - s0);
  if (tid < 128) cnt[tid] = 0;
  __syncthreads();
  for (int i=tid; i<m; i+=256)
    atomicAdd(&cnt[(unsigned int)(bbuf[s0+i] >> 32)], 1u);
  __syncthreads();
  if (tid < 128) excl[tid] = cnt[tid];
  __syncthreads();
  for (int off=1; off<128; off<<=1){
    unsigned int v = (tid < 128 && tid >= off) ? excl[tid-off] : 0;
    __syncthreads();
    if (tid < 128) excl[tid] += v;
    __syncthreads();
  }
  int node0 = b << 7;
  if (tid < 128){
    unsigned int ex = excl[tid] - cnt[tid];    // exclusive
    int n = node0 + tid;
    if (n < N) offs[n] = (int)(s0 + ex);
    excl[tid] = ex;
    cnt[tid] = 0;                              // reuse as cursor
  }
  __syncthreads();
  for (int i=tid; i<m; i+=256){
    unsigned long long v = bbuf[s0+i];
    unsigned int hi = (unsigned int)(v >> 32);
    unsigned int loc = atomicAdd(&cnt[hi], 1u);
    csr[s0 + excl[hi] + loc] = (unsigned int)v;
  }
}

// ---------------- prep: weight transposes (table + heads only) ----------------

__global__ void prep_transpose_kernel(const float* __restrict__ cf_w2,
                                      const float* __restrict__ et1_w,
                                      const float* __restrict__ nt1_w,
                                      const float* __restrict__ cf_w1,
                                      float* __restrict__ w2t,
                                      float* __restrict__ et1t,
                                      float* __restrict__ nt1t,
                                      float* __restrict__ w1t){
  int id = blockIdx.x*256 + threadIdx.x;
  if (id < 3*4096){
    int i = id >> 12, r = id & 4095;
    int k = r >> 6, j = r & 63;
    w2t[id]  = cf_w2[i*4096 + j*64 + k];
  }
  if (id < 128*64){
    int k = id >> 6, j = id & 63;
    et1t[id] = et1_w[j*128 + k];   // et1_w is [64][128]
  }
  if (id < 64*32){
    int k = id >> 5, j = id & 31;
    nt1t[id] = nt1_w[j*64 + k];    // nt1_w is [32][64]
  }
  if (id < 3*NC*DIM){              // cf_w1 [3][64][50] -> w1t [3][50][64]
    int l = id / (NC*DIM);
    int r = id - l*(NC*DIM);
    int m = r >> 6, k = r & 63;
    w1t[id] = cf_w1[l*DIM*NC + k*NC + m];
  }
}

// ---------------- filter table (bf16, nearest), wave = row, lane = feature ----------------

__global__ __launch_bounds__(256) void table_kernel(const float* __restrict__ edge_mask,
                                                    const float* __restrict__ w1t,   // [3][50][64]
                                                    const float* __restrict__ cf_b1,
                                                    const float* __restrict__ w2t,   // [3][64][64]
                                                    const float* __restrict__ cf_b2,
                                                    __hip_bfloat16* __restrict__ tabb){
  int row = blockIdx.x*4 + (threadIdx.x >> 6);
  if (row >= 3*TABP) return;
  int l = row / TABP, p = row - l*TABP;
  int lane = threadIdx.x & 63;
  float rbfv = 0.f;
  if (lane < NC){
    if (p == TABN+1) rbfv = edge_mask[lane];
    else {
      float d = (float)p * (5.0f/(float)TABN);
      float c = (lane == NC-1) ? 5.0f : (float)((double)lane * (5.0/49.0));
      float df = d - c;
      rbfv = __expf((float)(-1.0/(5.0/49.0)) * df * df);
    }
  }
  const float* W1 = w1t + l*NC*DIM;
  float t = cf_b1[l*DIM + lane];
  #pragma unroll 10
  for (int m=0;m<NC;m++)
    t = fmaf(rdl(rbfv, m), W1[m*64 + lane], t);
  float su = sp_f(t);
  const float* W2 = w2t + l*DIM*DIM;
  float h = cf_b2[l*DIM + lane];
  #pragma unroll 16
  for (int k=0;k<DIM;k++)
    h = fmaf(rdl(su, k), W2[k*64 + lane], h);
  tabb[((size_t)l*TABP + p)*DIM + lane] = __float2bfloat16(h);
}

// ---------------- node-side v4: lane = output feature, acc-resident loop order ----
// Block = 64 nodes, 4 waves; wave w owns nodes [16w,16w+16) = its own 16 panel
// rows (wave-local staging -> NO __syncthreads in the matmul chain).
// Loop order q(weight chunk) -> t(node): each weight float4 is loaded exactly
// once per q by construction (16 loads/matmul, can't be rematerialized into the
// hot loop), and the live set is acc[16] + wq + xv ~ 40-70 VGPR.

#define MM16(PANEL, WPTR, ACC) \
  float ACC[16]; \
  { \
    _Pragma("unroll") \
    for (int t0=0;t0<16;t0++) ACC[t0]=0.f; \
    const float* wp_ = (WPTR); \
    _Pragma("unroll 4") \
    for (int q=0;q<16;q++){ \
      float4 wq = *(const float4*)(wp_ + 4*q); \
      _Pragma("unroll") \
      for (int t=0;t<16;t++){ \
        float4 xv = *(const float4*)((PANEL) + t*64 + 4*q); \
        ACC[t] = fmaf(xv.x, wq.x, ACC[t]); \
        ACC[t] = fmaf(xv.y, wq.y, ACC[t]); \
        ACC[t] = fmaf(xv.z, wq.z, ACC[t]); \
        ACC[t] = fmaf(xv.w, wq.w, ACC[t]); \
      } \
    } \
  }

// node = emb[node_type]; nnb = bf16(node @ conv_w1[0]^T)
__global__ __launch_bounds__(256) void node_init4_kernel(const float* __restrict__ emb,
                                                         const int* __restrict__ node_type,
                                                         const float* __restrict__ cw1_0, // [j][k]
                                                         float* __restrict__ node,
                                                         __hip_bfloat16* __restrict__ nnb, int N){
  __shared__ float X[4096];
  __shared__ int types[64];
  int tid = threadIdx.x;
  int wv = tid >> 6, lane = tid & 63;
  int n0 = blockIdx.x*64;
  int nb = n0 + wv*16;
  if (tid < 64) types[tid] = (n0+tid < N) ? node_type[n0+tid] : 0;
  __syncthreads();
  float* xw = X + wv*1024;
  #pragma unroll
  for (int t=0;t<16;t++){
    int n = nb + t;
    float v = emb[(long)types[wv*16+t]*64 + lane];
    xw[t*64 + lane] = v;
    if (n < N) node[(long)n*64 + lane] = v;
  }
  MM16(xw, cw1_0 + lane*64, a0)
  #pragma unroll
  for (int t=0;t<16;t++){
    int n = nb + t;
    if (n < N) nnb[(long)n*64 + lane] = __float2bfloat16(a0[t]);
  }
}

// node += sp(agg@nl2^T+b2)@nl3^T+b3; optionally nnb = bf16(node_new @ cw1_next^T)
template<bool PRODUCE_NN>
__global__ __launch_bounds__(256) void node_update4_kernel(float* __restrict__ node,
                                                           const float* __restrict__ agg,
                                                           const float* __restrict__ nl2_w, // [j][k]
                                                           const float* __restrict__ nl2_b,
                                                           const float* __restrict__ nl3_w, // [j][k]
                                                           const float* __restrict__ nl3_b,
                                                           const float* __restrict__ cw1_next, // [j][k]
                                                           __hip_bfloat16* __restrict__ nnb, int N){
  __shared__ float X[4096];   // agg panel, later node_new panel (wave-local rows)
  __shared__ float S[4096];   // softplus panel (wave-local rows)
  int tid = threadIdx.x;
  int wv = tid >> 6, lane = tid & 63;
  int nb = blockIdx.x*64 + wv*16;
  float* xw = X + wv*1024;
  float* sw = S + wv*1024;
  // stage agg rows (wave-local; no block barrier needed anywhere)
  #pragma unroll
  for (int t=0;t<16;t++){
    int n = nb + t;
    xw[t*64 + lane] = (n < N) ? agg[(long)n*64 + lane] : 0.f;
  }
  // phase 1: S = sp(X @ nl2^T + b2)
  MM16(xw, nl2_w + lane*64, a1)
  float b2 = nl2_b[lane];
  #pragma unroll
  for (int t=0;t<16;t++) sw[t*64 + lane] = sp_f(a1[t] + b2);
  // phase 2: node_new = node + S @ nl3^T + b3
  MM16(sw, nl3_w + lane*64, a2)
  float b3 = nl3_b[lane];
  #pragma unroll
  for (int t=0;t<16;t++){
    int n = nb + t;
    float nv = 0.f;
    if (n < N){
      long gi = (long)n*64 + lane;
      nv = node[gi] + a2[t] + b3;
      node[gi] = nv;
    }
    xw[t*64 + lane] = nv;     // own rows: becomes node_new panel
  }
  if (PRODUCE_NN){
    MM16(xw, cw1_next + lane*64, a3)
    #pragma unroll
    for (int t=0;t<16;t++){
      int n = nb + t;
      if (n < N) nnb[(long)n*64 + lane] = __float2bfloat16(a3[t]);
    }
  }
}

// gather-aggregate: wave = 1 dst node, lane = feature; 4B csr, bf16 table + new_node
__global__ __launch_bounds__(256) void agg_kernel(const unsigned int* __restrict__ csr,
                                                  const int* __restrict__ offs,
                                                  const unsigned short* __restrict__ tab,  // [TABP][64] bf16
                                                  const unsigned short* __restrict__ nnb,  // bf16 bits
                                                  float* __restrict__ agg, int N){
  int n = blockIdx.x*4 + (threadIdx.x >> 6);
  int lane = threadIdx.x & 63;
  if (n >= N) return;
  int beg = offs[n], end = offs[n+1];
  float acc = 0.f;
  for (int c = beg; c < end; c += 64){
    int m = end - c; if (m > 64) m = 64;
    unsigned int pkv = csr[c + (lane < m ? lane : 0)];   // coalesced edge-list load
    int q = 0;
    for (; q + 8 <= m; q += 8){
      #pragma unroll
      for (int u=0; u<8; u++){
        unsigned int p = (unsigned int)__builtin_amdgcn_readlane((int)pkv, q+u); // SGPR
        int idx = p & 0xFFFF, s = p >> 16;
        float a  = __uint_as_float(((unsigned int)tab[idx*64 + lane]) << 16);
        float nn = __uint_as_float(((unsigned int)nnb[(long)s*64 + lane]) << 16);
        acc = fmaf(nn, a, acc);
      }
    }
    for (; q < m; q++){
      unsigned int p = (unsigned int)__builtin_amdgcn_readlane((int)pkv, q);
      int idx = p & 0xFFFF, s = p >> 16;
      float a  = __uint_as_float(((unsigned int)tab[idx*64 + lane]) << 16);
      float nn = __uint_as_float(((unsigned int)nnb[(long)s*64 + lane]) << 16);
      acc = fmaf(nn, a, acc);
    }
  }
  agg[(long)n*64 + lane] = acc;
}

// ---------------- heads ----------------

__global__ __launch_bounds__(256) void node_head_kernel(const float* __restrict__ node,
                                                        const int* __restrict__ nidx,
                                                        const float* __restrict__ nt1t,  // [64][32]
                                                        const float* __restrict__ nt1_b,
                                                        const float* __restrict__ nt2_w, // [3][32]
                                                        const float* __restrict__ nt2_b,
                                                        float* __restrict__ out, int NSEL){
  int r = __builtin_amdgcn_readfirstlane(blockIdx.x*4 + (threadIdx.x>>6));
  int lane = threadIdx.x & 63;
  if (r >= NSEL) return;
  long n = nidx[r];
  const float* x = node + n*64;                    // uniform -> s_loads
  float u = 0.f;
  if (lane < 32){
    u = nt1_b[lane];
    #pragma unroll
    for (int k=0;k<DIM;k++) u += x[k]*nt1t[k*32 + lane];
  }
  #pragma unroll
  for (int q=0;q<3;q++){
    float v = (lane < 32) ? u*nt2_w[q*32 + lane] : 0.f;
    #pragma unroll
    for (int o=32;o>=1;o>>=1) v += __shfl_xor(v, o);
    if (lane == 0) out[(long)r*3 + q] = nt2_b[q] + v;
  }
}

__global__ __launch_bounds__(256) void edge_head_kernel(const float* __restrict__ node,
                                                        const int* __restrict__ sidx,
                                                        const int* __restrict__ tidx,
                                                        const float* __restrict__ et1t, // [128][64]
                                                        const float* __restrict__ et1_b,
                                                        const float* __restrict__ et2_w,// [5][64]
                                                        const float* __restrict__ et2_b,
                                                        float* __restrict__ out, int ESEL){
  int wid = threadIdx.x >> 6, lane = threadIdx.x & 63;
  int r0 = (blockIdx.x*4 + wid)*4;
  if (r0 >= ESEL) return;
  float xs[4], xt[4], acc[4];
  #pragma unroll
  for (int i=0;i<4;i++){
    int r = r0+i < ESEL ? r0+i : ESEL-1;
    long s = sidx[r], t = tidx[r];
    xs[i] = node[s*64 + lane];
    xt[i] = node[t*64 + lane];
    acc[i] = et1_b[lane];
  }
  #pragma unroll 16
  for (int k=0;k<DIM;k++){
    float w1 = et1t[k*64 + lane];
    float w2 = et1t[(64+k)*64 + lane];
    #pragma unroll
    for (int i=0;i<4;i++){
      acc[i] = fmaf(rdl(xs[i], k), w1, acc[i]);
      acc[i] = fmaf(rdl(xt[i], k), w2, acc[i]);
    }
  }
  #pragma unroll
  for (int i=0;i<4;i++){
    if (r0+i >= ESEL) break;
    #pragma unroll
    for (int q=0;q<5;q++){
      float v = acc[i]*et2_w[q*64 + lane];
      #pragma unroll
      for (int o=32;o>=1;o>>=1) v += __shfl_xor(v, o);
      if (lane == 0) out[(long)(r0+i)*5 + q] = et2_b[q] + v;
    }
  }
}

// ---------------- launch ----------------

extern "C" void kernel_launch(void* const* d_in, const int* in_sizes, int n_in,
                              void* d_out, int out_size, void* d_ws, size_t ws_size,
                              hipStream_t stream){
  const float* emb      = (const float*)d_in[0];
  const float* dist     = (const float*)d_in[1];
  const float* edge_mask= (const float*)d_in[2];
  const float* conv_w1  = (const float*)d_in[3];
  const float* cf_w1    = (const float*)d_in[4];
  const float* cf_b1    = (const float*)d_in[5];
  const float* cf_w2    = (const float*)d_in[6];
  const float* cf_b2    = (const float*)d_in[7];
  const float* nl2_w    = (const float*)d_in[8];
  const float* nl2_b    = (const float*)d_in[9];
  const float* nl3_w    = (const float*)d_in[10];
  const float* nl3_b    = (const float*)d_in[11];
  const float* nt1_w    = (const float*)d_in[12];
  const float* nt1_b    = (const float*)d_in[13];
  const float* nt2_w    = (const float*)d_in[14];
  const float* nt2_b    = (const float*)d_in[15];
  const float* et1_w    = (const float*)d_in[16];
  const float* et1_b    = (const float*)d_in[17];
  const float* et2_w    = (const float*)d_in[18];
  const float* et2_b    = (const float*)d_in[19];
  const int* node_type  = (const int*)d_in[20];
  const int* src        = (const int*)d_in[21];
  const int* dst        = (const int*)d_in[22];
  const int* sel        = (const int*)d_in[23];
  const int* node_index = (const int*)d_in[24];
  const int* source_index = (const int*)d_in[25];
  const int* target_index = (const int*)d_in[26];

  int E    = in_sizes[1];
  int N    = in_sizes[20];
  int K    = in_sizes[23];
  int NSEL = in_sizes[24];
  int ESEL = in_sizes[25];

  int NB  = (N + 127) >> 7;           // buckets of 128 nodes
  int FW  = (E + 31) >> 5;            // flag words
  int nbE = (E + EPB - 1) / EPB;      // CSR-build blocks

  size_t N64 = (size_t)N*64;
  // bbuf (E u64) first for 8B alignment; agg aliases it (lifetimes disjoint)
  unsigned long long* bbuf = (unsigned long long*)d_ws;
  float* agg = (float*)d_ws;
  size_t aggsz = ((size_t)2*E > N64) ? (size_t)2*E : N64;   // float units
  float* p = (float*)d_ws + aggsz;
  float* node     = p; p += N64;
  __hip_bfloat16* nnb = (__hip_bfloat16*)p; p += N64/2;     // bf16 new_node
  float* w2t      = p; p += 3*4096;
  float* et1t     = p; p += 128*64;
  float* nt1t     = p; p += 64*32;
  float* w1t      = p; p += 3*NC*DIM;
  __hip_bfloat16* tabb = (__hip_bfloat16*)p; p += (size_t)3*TABP*DIM/2;
  unsigned int* csr      = (unsigned int*)p; p += E;
  unsigned int* flagbits = (unsigned int*)p; p += FW;
  unsigned int* gbcnt    = (unsigned int*)p; p += NB;
  unsigned int* bscan    = (unsigned int*)p; p += NB+1;
  unsigned int* gcursor  = (unsigned int*)p; p += NB;
  int* offs              = (int*)p; p += N+1;

  // CSR build: two-level LDS counting sort
  hipMemsetAsync(gbcnt, 0, (size_t)NB*sizeof(int), stream);
  bhist_kernel<<<nbE, 256, 0, stream>>>(dst, gbcnt, flagbits, E, NB, FW);
  sel_mark_kernel<<<(K+255)/256, 256, 0, stream>>>(sel, flagbits, K);
  prep_transpose_kernel<<<48, 256, 0, stream>>>(cf_w2, et1_w, nt1_w, cf_w1,
                                                w2t, et1t, nt1t, w1t);
  bscan_kernel<<<1, NBMAX, 0, stream>>>(gbcnt, bscan, gcursor, offs, NB, N, E);
  passA_kernel<<<nbE, 256, 0, stream>>>(dst, src, dist, flagbits, gcursor, bbuf, E, NB);
  passB_kernel<<<NB, 256, 0, stream>>>(bbuf, bscan, offs, csr, N);
  // filter tables (3 layers, wave=row, nearest-neighbor bf16)
  table_kernel<<<(3*TABP+3)/4, 256, 0, stream>>>(edge_mask, w1t, cf_b1, w2t, cf_b2, tabb);

  int nbP  = (N+63)/64;    // node-panel blocks (64 nodes/block, 4 waves)
  int nb_agg = (N+3)/4;    // 4 waves/block x 1 node/wave
  node_init4_kernel<<<nbP, 256, 0, stream>>>(emb, node_type, conv_w1, node, nnb, N);
  for (int l=0;l<3;l++){
    agg_kernel<<<nb_agg, 256, 0, stream>>>(csr, offs,
        (const unsigned short*)(tabb + (size_t)l*TABP*DIM),
        (const unsigned short*)nnb, agg, N);
    if (l < 2)
      node_update4_kernel<true><<<nbP, 256, 0, stream>>>(node, agg, nl2_w + l*4096, nl2_b + l*64,
          nl3_w + l*4096, nl3_b + l*64, conv_w1 + (l+1)*4096, nnb, N);
    else
      node_update4_kernel<false><<<nbP, 256, 0, stream>>>(node, agg, nl2_w + l*4096, nl2_b + l*64,
          nl3_w + l*4096, nl3_b + l*64, nullptr, nullptr, N);
  }

  node_head_kernel<<<(NSEL+3)/4, 256, 0, stream>>>(node, node_index,
      nt1t, nt1_b, nt2_w, nt2_b, (float*)d_out, NSEL);
  edge_head_kernel<<<(ESEL+15)/16, 256, 0, stream>>>(node, source_index, target_index,
      et1t, et1_b, et2_w, et2_b, (float*)d_out + (size_t)NSEL*3, ESEL);
}

// Round 13
// 337.261 us; speedup vs baseline: 1.6401x; 1.1307x over previous
//
#include <hip/hip_runtime.h>
#include <hip/hip_bf16.h>

#define DIM 64
#define NC 50
#define TABN 4096
#define TABP (TABN + 2)   // rows 0..4096 = h at p*5/4096, row 4097 = mask row
#define EPB 4096          // edges per block in CSR build
#define NBMAX 512         // max buckets (N <= 65536)

typedef short bf16x8 __attribute__((ext_vector_type(8)));
typedef float f32x4  __attribute__((ext_vector_type(4)));
#define MFMA(a,b,c) __builtin_amdgcn_mfma_f32_16x16x32_bf16(a,b,c,0,0,0)

__device__ __forceinline__ float sp_f(float x){
  // torch Softplus(beta=0.5, threshold=14): 2*log(1+exp(0.5x)), linear when 0.5*x>14
  float e = __expf(0.5f*x);
  float s = 2.0f*__logf(1.0f+e);
  return x > 28.0f ? x : s;
}

__device__ __forceinline__ float rdl(float v, int l){
  return __int_as_float(__builtin_amdgcn_readlane(__float_as_int(v), l));
}

__device__ __forceinline__ unsigned short b16(float x){
  __hip_bfloat16 h = __float2bfloat16(x);
  return __builtin_bit_cast(unsigned short, h);
}

// split x into hi + lo bf16 (lo = bf16(x - float(hi))) -> ~fp32 via 3-term MFMA
__device__ __forceinline__ void wsplit(float x, unsigned short& h, unsigned short& l){
  h = b16(x);
  float hf = __uint_as_float(((unsigned int)h) << 16);
  l = b16(x - hf);
}

// ---------------- CSR build: two-level LDS counting sort ----------------

__global__ __launch_bounds__(256) void bhist_kernel(const int* __restrict__ dst,
                                                    unsigned int* __restrict__ gbcnt,
                                                    unsigned int* __restrict__ flagbits,
                                                    int E, int NB, int FW){
  __shared__ unsigned int cnt[NBMAX];
  int tid = threadIdx.x;
  for (int b=tid; b<NB; b+=256) cnt[b] = 0;
  __syncthreads();
  int e0 = blockIdx.x*EPB, eend = min(e0+EPB, E);
  for (int e=e0+tid; e<eend; e+=256) atomicAdd(&cnt[dst[e]>>7], 1u);
  for (int w = blockIdx.x*256+tid; w < FW; w += gridDim.x*256) flagbits[w] = 0;
  __syncthreads();
  for (int b=tid; b<NB; b+=256) if (cnt[b]) atomicAdd(&gbcnt[b], cnt[b]);
}

__global__ void sel_mark_kernel(const int* __restrict__ sel,
                                unsigned int* __restrict__ flagbits, int K){
  int id = blockIdx.x*256 + threadIdx.x;
  if (id < K){ int e = sel[id]; atomicOr(&flagbits[e>>5], 1u << (e&31)); }
}

__global__ __launch_bounds__(NBMAX) void bscan_kernel(const unsigned int* __restrict__ gbcnt,
                                                      unsigned int* __restrict__ bscan,
                                                      unsigned int* __restrict__ gcursor,
                                                      int* __restrict__ offs,
                                                      int NB, int N, int E){
  __shared__ unsigned int s[NBMAX];
  int tid = threadIdx.x;
  unsigned int v = (tid < NB) ? gbcnt[tid] : 0;
  s[tid] = v;
  __syncthreads();
  for (int off=1; off<NBMAX; off<<=1){
    unsigned int u = (tid >= off) ? s[tid-off] : 0;
    __syncthreads();
    s[tid] += u;
    __syncthreads();
  }
  unsigned int excl = s[tid] - v;
  if (tid < NB){ bscan[tid] = excl; gcursor[tid] = excl; }
  if (tid == NB-1) bscan[NB] = excl + v;
  if (tid == 0) offs[N] = E;
}

__global__ __launch_bounds__(256) void passA_kernel(const int* __restrict__ dst,
                                                    const int* __restrict__ src,
                                                    const float* __restrict__ dist,
                                                    const unsigned int* __restrict__ flagbits,
                                                    unsigned int* __restrict__ gcursor,
                                                    unsigned long long* __restrict__ bbuf,
                                                    int E, int NB){
  __shared__ unsigned int cnt[NBMAX];
  __shared__ unsigned int base[NBMAX];
  int tid = threadIdx.x;
  for (int b=tid; b<NB; b+=256) cnt[b] = 0;
  __syncthreads();
  int e0 = blockIdx.x*EPB, eend = min(e0+EPB, E);
  for (int e=e0+tid; e<eend; e+=256) atomicAdd(&cnt[dst[e]>>7], 1u);
  __syncthreads();
  for (int b=tid; b<NB; b+=256){
    unsigned int c = cnt[b];
    base[b] = c ? atomicAdd(&gcursor[b], c) : 0u;
    cnt[b] = 0;                       // reuse as local cursor
  }
  __syncthreads();
  for (int e=e0+tid; e<eend; e+=256){
    int d = dst[e];
    int b = d >> 7;
    unsigned int loc = atomicAdd(&cnt[b], 1u);
    float t = fminf(dist[e], 5.f) * ((float)TABN/5.0f);
    int idx = (int)(t + 0.5f); if (idx > TABN) idx = TABN;   // nearest grid point
    if ((flagbits[e>>5] >> (e&31)) & 1u) idx = TABN+1;       // mask row
    unsigned int lo = ((unsigned int)src[e] << 16) | (unsigned int)idx; // src<65536
    unsigned int hi = (unsigned int)(d & 127);
    bbuf[base[b] + loc] = ((unsigned long long)hi << 32) | lo;
  }
}

__global__ __launch_bounds__(256) void passB_kernel(const unsigned long long* __restrict__ bbuf,
                                                    const unsigned int* __restrict__ bscan,
                                                    int* __restrict__ offs,
                                                    unsigned int* __restrict__ csr,
                                                    int N){
  __shared__ unsigned int cnt[128];
  __shared__ unsigned int excl[128];
  int b = blockIdx.x, tid = threadIdx.x;
  unsigned int s0 = bscan[b];
  int m = (int)(bscan[b+1] - s0);
  if (tid < 128) cnt[tid] = 0;
  __syncthreads();
  for (int i=tid; i<m; i+=256)
    atomicAdd(&cnt[(unsigned int)(bbuf[s0+i] >> 32)], 1u);
  __syncthreads();
  if (tid < 128) excl[tid] = cnt[tid];
  __syncthreads();
  for (int off=1; off<128; off<<=1){
    unsigned int v = (tid < 128 && tid >= off) ? excl[tid-off] : 0;
    __syncthreads();
    if (tid < 128) excl[tid] += v;
    __syncthreads();
  }
  int node0 = b << 7;
  if (tid < 128){
    unsigned int ex = excl[tid] - cnt[tid];    // exclusive
    int n = node0 + tid;
    if (n < N) offs[n] = (int)(s0 + ex);
    excl[tid] = ex;
    cnt[tid] = 0;                              // reuse as cursor
  }
  __syncthreads();
  for (int i=tid; i<m; i+=256){
    unsigned long long v = bbuf[s0+i];
    unsigned int hi = (unsigned int)(v >> 32);
    unsigned int loc = atomicAdd(&cnt[hi], 1u);
    csr[s0 + excl[hi] + loc] = (unsigned int)v;
  }
}

// ---------------- prep: weight transposes (table + heads only) ----------------

__global__ void prep_transpose_kernel(const float* __restrict__ cf_w2,
                                      const float* __restrict__ et1_w,
                                      const float* __restrict__ nt1_w,
                                      const float* __restrict__ cf_w1,
                                      float* __restrict__ w2t,
                                      float* __restrict__ et1t,
                                      float* __restrict__ nt1t,
                                      float* __restrict__ w1t){
  int id = blockIdx.x*256 + threadIdx.x;
  if (id < 3*4096){
    int i = id >> 12, r = id & 4095;
    int k = r >> 6, j = r & 63;
    w2t[id]  = cf_w2[i*4096 + j*64 + k];
  }
  if (id < 128*64){
    int k = id >> 6, j = id & 63;
    et1t[id] = et1_w[j*128 + k];   // et1_w is [64][128]
  }
  if (id < 64*32){
    int k = id >> 5, j = id & 31;
    nt1t[id] = nt1_w[j*64 + k];    // nt1_w is [32][64]
  }
  if (id < 3*NC*DIM){              // cf_w1 [3][64][50] -> w1t [3][50][64]
    int l = id / (NC*DIM);
    int r = id - l*(NC*DIM);
    int m = r >> 6, k = r & 63;
    w1t[id] = cf_w1[l*DIM*NC + k*NC + m];
  }
}

// ---------------- filter table (bf16, nearest), wave = row, lane = feature ----------------

__global__ __launch_bounds__(256) void table_kernel(const float* __restrict__ edge_mask,
                                                    const float* __restrict__ w1t,   // [3][50][64]
                                                    const float* __restrict__ cf_b1,
                                                    const float* __restrict__ w2t,   // [3][64][64]
                                                    const float* __restrict__ cf_b2,
                                                    __hip_bfloat16* __restrict__ tabb){
  int row = blockIdx.x*4 + (threadIdx.x >> 6);
  if (row >= 3*TABP) return;
  int l = row / TABP, p = row - l*TABP;
  int lane = threadIdx.x & 63;
  float rbfv = 0.f;
  if (lane < NC){
    if (p == TABN+1) rbfv = edge_mask[lane];
    else {
      float d = (float)p * (5.0f/(float)TABN);
      float c = (lane == NC-1) ? 5.0f : (float)((double)lane * (5.0/49.0));
      float df = d - c;
      rbfv = __expf((float)(-1.0/(5.0/49.0)) * df * df);
    }
  }
  const float* W1 = w1t + l*NC*DIM;
  float t = cf_b1[l*DIM + lane];
  #pragma unroll 10
  for (int m=0;m<NC;m++)
    t = fmaf(rdl(rbfv, m), W1[m*64 + lane], t);
  float su = sp_f(t);
  const float* W2 = w2t + l*DIM*DIM;
  float h = cf_b2[l*DIM + lane];
  #pragma unroll 16
  for (int k=0;k<DIM;k++)
    h = fmaf(rdl(su, k), W2[k*64 + lane], h);
  tabb[((size_t)l*TABP + p)*DIM + lane] = __float2bfloat16(h);
}

// ---------------- node-side v6: split-precision MFMA 16x16x32 bf16 ----------------
// Same geometry as v5 (block=64 nodes, 4 waves, wave = 16-row M-strip, swizzled
// LDS panels byte^=(row&7)<<4), but each matrix is stored as TWO bf16 panels
// (hi, lo) with x = hi + lo; product uses 3 terms Ah*Wh + Ah*Wl + Al*Wh ->
// ~fp32 accuracy (dropped Al*Wl ~ 2^-16). f32 node residual stays exact.
// C/D layout: D[row=(l>>4)*4+reg][col=(l&15)]  [learn_hip m89/m91]

__device__ __forceinline__ void stage_w2(const float* __restrict__ src,
                                         char* hi, char* lo, int tid){
  #pragma unroll
  for (int ii=0; ii<8; ii++){
    int i = tid + ii*256;            // pair index, 2048 pairs
    int row = i >> 5, cp = i & 31;
    float2 v = *(const float2*)(src + row*64 + cp*2);
    unsigned short hx,lx,hy,ly;
    wsplit(v.x, hx, lx);
    wsplit(v.y, hy, ly);
    int off = row*128 + ((cp*4) ^ ((row&7)<<4));
    *(unsigned int*)(hi + off) = (unsigned int)hx | ((unsigned int)hy << 16);
    *(unsigned int*)(lo + off) = (unsigned int)lx | ((unsigned int)ly << 16);
  }
}

__device__ __forceinline__ bf16x8 ldfrag(const char* base, int rowbase, int ks, int lane){
  int r = lane & 15;
  int off = (ks<<6) + ((lane>>4)<<4);
  return *(const bf16x8*)(base + (rowbase + r)*128 + (off ^ ((r & 7)<<4)));
}

__device__ __forceinline__ void stx(char* XH, char* XLo, int row, int col, float v){
  unsigned short h,l;
  wsplit(v, h, l);
  int off = row*128 + ((col*2) ^ ((row&7)<<4));
  *(unsigned short*)(XH + off) = h;
  *(unsigned short*)(XLo + off) = l;
}

// 6-term MFMA product of strip [mb..mb+16) x W^T quadrant nt
#define MM6(XH_, XLo_, WH_, WLo_, NT, ACC) \
  { ACC = MFMA(ah0, ldfrag(WH_,  (NT)*16, 0, lane), ACC); \
    ACC = MFMA(ah1, ldfrag(WH_,  (NT)*16, 1, lane), ACC); \
    ACC = MFMA(ah0, ldfrag(WLo_, (NT)*16, 0, lane), ACC); \
    ACC = MFMA(ah1, ldfrag(WLo_, (NT)*16, 1, lane), ACC); \
    ACC = MFMA(al0, ldfrag(WH_,  (NT)*16, 0, lane), ACC); \
    ACC = MFMA(al1, ldfrag(WH_,  (NT)*16, 1, lane), ACC); }

#define LDA(XH_, XLo_) \
  bf16x8 ah0 = ldfrag(XH_, mb, 0, lane), ah1 = ldfrag(XH_, mb, 1, lane); \
  bf16x8 al0 = ldfrag(XLo_, mb, 0, lane), al1 = ldfrag(XLo_, mb, 1, lane);

// node = emb[node_type]; nnb = bf16(node @ conv_w1[0]^T)
__global__ __launch_bounds__(256) void node_init6_kernel(const float* __restrict__ emb,
                                                         const int* __restrict__ node_type,
                                                         const float* __restrict__ cw1_0, // [j][k]
                                                         float* __restrict__ node,
                                                         __hip_bfloat16* __restrict__ nnb, int N){
  __shared__ __align__(16) char WL[16384];
  __shared__ __align__(16) char XP[16384];
  char *WH = WL, *WLo = WL + 8192;
  char *XH = XP, *XLo = XP + 8192;
  int tid = threadIdx.x, lane = tid & 63, wv = tid >> 6;
  int nb = blockIdx.x*64, mb = wv*16;
  stage_w2(cw1_0, WH, WLo, tid);
  #pragma unroll
  for (int t=0;t<16;t++){
    int row = mb + t, n = nb + row;
    int ty = (n < N) ? node_type[n] : 0;
    float v = emb[(long)ty*64 + lane];
    if (n < N) node[(long)n*64 + lane] = v;
    stx(XH, XLo, row, lane, v);
  }
  __syncthreads();
  LDA(XH, XLo)
  #pragma unroll
  for (int nt=0; nt<4; nt++){
    f32x4 acc = {0.f,0.f,0.f,0.f};
    MM6(XH, XLo, WH, WLo, nt, acc)
    int col = nt*16 + (lane&15);
    #pragma unroll
    for (int v=0; v<4; v++){
      int n = nb + mb + ((lane>>4)<<2) + v;
      if (n < N) ((unsigned short*)nnb)[(long)n*64 + col] = b16(acc[v]);
    }
  }
}

// node += sp(agg@nl2^T+b2)@nl3^T+b3; optionally nnb = bf16(node_new @ cw1_next^T)
template<bool PRODUCE_NN>
__global__ __launch_bounds__(256) void node_update6_kernel(float* __restrict__ node,
                                                           const float* __restrict__ agg,
                                                           const float* __restrict__ nl2_w, // [j][k]
                                                           const float* __restrict__ nl2_b,
                                                           const float* __restrict__ nl3_w, // [j][k]
                                                           const float* __restrict__ nl3_b,
                                                           const float* __restrict__ cw1_next, // [j][k]
                                                           __hip_bfloat16* __restrict__ nnb, int N){
  __shared__ __align__(16) char WL[49152];   // 3 matrices x (hi,lo) panels
  __shared__ __align__(16) char XP[16384];   // activation (hi,lo)
  char *W2H = WL,          *W2L = WL + 8192;
  char *W3H = WL + 16384,  *W3L = WL + 24576;
  char *W1H = WL + 32768,  *W1L = WL + 40960;
  char *XH = XP, *XLo = XP + 8192;
  int tid = threadIdx.x, lane = tid & 63, wv = tid >> 6;
  int nb = blockIdx.x*64, mb = wv*16;
  stage_w2(nl2_w, W2H, W2L, tid);
  stage_w2(nl3_w, W3H, W3L, tid);
  if (PRODUCE_NN) stage_w2(cw1_next, W1H, W1L, tid);
  // stage agg rows (wave-local)
  #pragma unroll
  for (int t=0;t<16;t++){
    int row = mb + t, n = nb + row;
    float v = (n < N) ? agg[(long)n*64 + lane] : 0.f;
    stx(XH, XLo, row, lane, v);
  }
  __syncthreads();
  // matmul1: S = sp(X @ nl2^T + b2) -> back into X panels (own rows)
  {
    LDA(XH, XLo)
    #pragma unroll
    for (int nt=0; nt<4; nt++){
      float bb = nl2_b[nt*16 + (lane&15)];
      f32x4 acc = {bb,bb,bb,bb};
      MM6(XH, XLo, W2H, W2L, nt, acc)
      int col = nt*16 + (lane&15);
      #pragma unroll
      for (int v=0; v<4; v++){
        int row = mb + ((lane>>4)<<2) + v;
        stx(XH, XLo, row, col, sp_f(acc[v]));
      }
    }
  }
  // matmul2: node_new = node + S @ nl3^T + b3 -> node (f32) and X panels
  {
    LDA(XH, XLo)
    #pragma unroll
    for (int nt=0; nt<4; nt++){
      float bb = nl3_b[nt*16 + (lane&15)];
      f32x4 acc = {bb,bb,bb,bb};
      MM6(XH, XLo, W3H, W3L, nt, acc)
      int col = nt*16 + (lane&15);
      #pragma unroll
      for (int v=0; v<4; v++){
        int row = mb + ((lane>>4)<<2) + v;
        int n = nb + row;
        float nv = 0.f;
        if (n < N){
          long g = (long)n*64 + col;
          nv = node[g] + acc[v];
          node[g] = nv;
        }
        stx(XH, XLo, row, col, nv);
      }
    }
  }
  if (PRODUCE_NN){
    LDA(XH, XLo)
    #pragma unroll
    for (int nt=0; nt<4; nt++){
      f32x4 acc = {0.f,0.f,0.f,0.f};
      MM6(XH, XLo, W1H, W1L, nt, acc)
      int col = nt*16 + (lane&15);
      #pragma unroll
      for (int v=0; v<4; v++){
        int n = nb + mb + ((lane>>4)<<2) + v;
        if (n < N) ((unsigned short*)nnb)[(long)n*64 + col] = b16(acc[v]);
      }
    }
  }
}

// gather-aggregate: wave = 1 dst node, lane = feature; 4B csr, bf16 table + new_node
__global__ __launch_bounds__(256) void agg_kernel(const unsigned int* __restrict__ csr,
                                                  const int* __restrict__ offs,
                                                  const unsigned short* __restrict__ tab,  // [TABP][64] bf16
                                                  const unsigned short* __restrict__ nnb,  // bf16 bits
                                                  float* __restrict__ agg, int N){
  int n = blockIdx.x*4 + (threadIdx.x >> 6);
  int lane = threadIdx.x & 63;
  if (n >= N) return;
  int beg = offs[n], end = offs[n+1];
  float acc = 0.f;
  for (int c = beg; c < end; c += 64){
    int m = end - c; if (m > 64) m = 64;
    unsigned int pkv = csr[c + (lane < m ? lane : 0)];   // coalesced edge-list load
    int q = 0;
    for (; q + 8 <= m; q += 8){
      #pragma unroll
      for (int u=0; u<8; u++){
        unsigned int p = (unsigned int)__builtin_amdgcn_readlane((int)pkv, q+u); // SGPR
        int idx = p & 0xFFFF, s = p >> 16;
        float a  = __uint_as_float(((unsigned int)tab[idx*64 + lane]) << 16);
        float nn = __uint_as_float(((unsigned int)nnb[(long)s*64 + lane]) << 16);
        acc = fmaf(nn, a, acc);
      }
    }
    for (; q < m; q++){
      unsigned int p = (unsigned int)__builtin_amdgcn_readlane((int)pkv, q);
      int idx = p & 0xFFFF, s = p >> 16;
      float a  = __uint_as_float(((unsigned int)tab[idx*64 + lane]) << 16);
      float nn = __uint_as_float(((unsigned int)nnb[(long)s*64 + lane]) << 16);
      acc = fmaf(nn, a, acc);
    }
  }
  agg[(long)n*64 + lane] = acc;
}

// ---------------- heads ----------------

__global__ __launch_bounds__(256) void node_head_kernel(const float* __restrict__ node,
                                                        const int* __restrict__ nidx,
                                                        const float* __restrict__ nt1t,  // [64][32]
                                                        const float* __restrict__ nt1_b,
                                                        const float* __restrict__ nt2_w, // [3][32]
                                                        const float* __restrict__ nt2_b,
                                                        float* __restrict__ out, int NSEL){
  int r = __builtin_amdgcn_readfirstlane(blockIdx.x*4 + (threadIdx.x>>6));
  int lane = threadIdx.x & 63;
  if (r >= NSEL) return;
  long n = nidx[r];
  const float* x = node + n*64;                    // uniform -> s_loads
  float u = 0.f;
  if (lane < 32){
    u = nt1_b[lane];
    #pragma unroll
    for (int k=0;k<DIM;k++) u += x[k]*nt1t[k*32 + lane];
  }
  #pragma unroll
  for (int q=0;q<3;q++){
    float v = (lane < 32) ? u*nt2_w[q*32 + lane] : 0.f;
    #pragma unroll
    for (int o=32;o>=1;o>>=1) v += __shfl_xor(v, o);
    if (lane == 0) out[(long)r*3 + q] = nt2_b[q] + v;
  }
}

__global__ __launch_bounds__(256) void edge_head_kernel(const float* __restrict__ node,
                                                        const int* __restrict__ sidx,
                                                        const int* __restrict__ tidx,
                                                        const float* __restrict__ et1t, // [128][64]
                                                        const float* __restrict__ et1_b,
                                                        const float* __restrict__ et2_w,// [5][64]
                                                        const float* __restrict__ et2_b,
                                                        float* __restrict__ out, int ESEL){
  int wid = threadIdx.x >> 6, lane = threadIdx.x & 63;
  int r0 = (blockIdx.x*4 + wid)*4;
  if (r0 >= ESEL) return;
  float xs[4], xt[4], acc[4];
  #pragma unroll
  for (int i=0;i<4;i++){
    int r = r0+i < ESEL ? r0+i : ESEL-1;
    long s = sidx[r], t = tidx[r];
    xs[i] = node[s*64 + lane];
    xt[i] = node[t*64 + lane];
    acc[i] = et1_b[lane];
  }
  #pragma unroll 16
  for (int k=0;k<DIM;k++){
    float w1 = et1t[k*64 + lane];
    float w2 = et1t[(64+k)*64 + lane];
    #pragma unroll
    for (int i=0;i<4;i++){
      acc[i] = fmaf(rdl(xs[i], k), w1, acc[i]);
      acc[i] = fmaf(rdl(xt[i], k), w2, acc[i]);
    }
  }
  #pragma unroll
  for (int i=0;i<4;i++){
    if (r0+i >= ESEL) break;
    #pragma unroll
    for (int q=0;q<5;q++){
      float v = acc[i]*et2_w[q*64 + lane];
      #pragma unroll
      for (int o=32;o>=1;o>>=1) v += __shfl_xor(v, o);
      if (lane == 0) out[(long)(r0+i)*5 + q] = et2_b[q] + v;
    }
  }
}

// ---------------- launch ----------------

extern "C" void kernel_launch(void* const* d_in, const int* in_sizes, int n_in,
                              void* d_out, int out_size, void* d_ws, size_t ws_size,
                              hipStream_t stream){
  const float* emb      = (const float*)d_in[0];
  const float* dist     = (const float*)d_in[1];
  const float* edge_mask= (const float*)d_in[2];
  const float* conv_w1  = (const float*)d_in[3];
  const float* cf_w1    = (const float*)d_in[4];
  const float* cf_b1    = (const float*)d_in[5];
  const float* cf_w2    = (const float*)d_in[6];
  const float* cf_b2    = (const float*)d_in[7];
  const float* nl2_w    = (const float*)d_in[8];
  const float* nl2_b    = (const float*)d_in[9];
  const float* nl3_w    = (const float*)d_in[10];
  const float* nl3_b    = (const float*)d_in[11];
  const float* nt1_w    = (const float*)d_in[12];
  const float* nt1_b    = (const float*)d_in[13];
  const float* nt2_w    = (const float*)d_in[14];
  const float* nt2_b    = (const float*)d_in[15];
  const float* et1_w    = (const float*)d_in[16];
  const float* et1_b    = (const float*)d_in[17];
  const float* et2_w    = (const float*)d_in[18];
  const float* et2_b    = (const float*)d_in[19];
  const int* node_type  = (const int*)d_in[20];
  const int* src        = (const int*)d_in[21];
  const int* dst        = (const int*)d_in[22];
  const int* sel        = (const int*)d_in[23];
  const int* node_index = (const int*)d_in[24];
  const int* source_index = (const int*)d_in[25];
  const int* target_index = (const int*)d_in[26];

  int E    = in_sizes[1];
  int N    = in_sizes[20];
  int K    = in_sizes[23];
  int NSEL = in_sizes[24];
  int ESEL = in_sizes[25];

  int NB  = (N + 127) >> 7;           // buckets of 128 nodes
  int FW  = (E + 31) >> 5;            // flag words
  int nbE = (E + EPB - 1) / EPB;      // CSR-build blocks

  size_t N64 = (size_t)N*64;
  // bbuf (E u64) first for 8B alignment; agg aliases it (lifetimes disjoint)
  unsigned long long* bbuf = (unsigned long long*)d_ws;
  float* agg = (float*)d_ws;
  size_t aggsz = ((size_t)2*E > N64) ? (size_t)2*E : N64;   // float units
  float* p = (float*)d_ws + aggsz;
  float* node     = p; p += N64;
  __hip_bfloat16* nnb = (__hip_bfloat16*)p; p += N64/2;     // bf16 new_node
  float* w2t      = p; p += 3*4096;
  float* et1t     = p; p += 128*64;
  float* nt1t     = p; p += 64*32;
  float* w1t      = p; p += 3*NC*DIM;
  __hip_bfloat16* tabb = (__hip_bfloat16*)p; p += (size_t)3*TABP*DIM/2;
  unsigned int* csr      = (unsigned int*)p; p += E;
  unsigned int* flagbits = (unsigned int*)p; p += FW;
  unsigned int* gbcnt    = (unsigned int*)p; p += NB;
  unsigned int* bscan    = (unsigned int*)p; p += NB+1;
  unsigned int* gcursor  = (unsigned int*)p; p += NB;
  int* offs              = (int*)p; p += N+1;

  // CSR build: two-level LDS counting sort
  hipMemsetAsync(gbcnt, 0, (size_t)NB*sizeof(int), stream);
  bhist_kernel<<<nbE, 256, 0, stream>>>(dst, gbcnt, flagbits, E, NB, FW);
  sel_mark_kernel<<<(K+255)/256, 256, 0, stream>>>(sel, flagbits, K);
  prep_transpose_kernel<<<48, 256, 0, stream>>>(cf_w2, et1_w, nt1_w, cf_w1,
                                                w2t, et1t, nt1t, w1t);
  bscan_kernel<<<1, NBMAX, 0, stream>>>(gbcnt, bscan, gcursor, offs, NB, N, E);
  passA_kernel<<<nbE, 256, 0, stream>>>(dst, src, dist, flagbits, gcursor, bbuf, E, NB);
  passB_kernel<<<NB, 256, 0, stream>>>(bbuf, bscan, offs, csr, N);
  // filter tables (3 layers, wave=row, nearest-neighbor bf16)
  table_kernel<<<(3*TABP+3)/4, 256, 0, stream>>>(edge_mask, w1t, cf_b1, w2t, cf_b2, tabb);

  int nbP  = (N+63)/64;    // node-panel blocks (64 nodes/block, 4 waves)
  int nb_agg = (N+3)/4;    // 4 waves/block x 1 node/wave
  node_init6_kernel<<<nbP, 256, 0, stream>>>(emb, node_type, conv_w1, node, nnb, N);
  for (int l=0;l<3;l++){
    agg_kernel<<<nb_agg, 256, 0, stream>>>(csr, offs,
        (const unsigned short*)(tabb + (size_t)l*TABP*DIM),
        (const unsigned short*)nnb, agg, N);
    if (l < 2)
      node_update6_kernel<true><<<nbP, 256, 0, stream>>>(node, agg, nl2_w + l*4096, nl2_b + l*64,
          nl3_w + l*4096, nl3_b + l*64, conv_w1 + (l+1)*4096, nnb, N);
    else
      node_update6_kernel<false><<<nbP, 256, 0, stream>>>(node, agg, nl2_w + l*4096, nl2_b + l*64,
          nl3_w + l*4096, nl3_b + l*64, nullptr, nullptr, N);
  }

  node_head_kernel<<<(NSEL+3)/4, 256, 0, stream>>>(node, node_index,
      nt1t, nt1_b, nt2_w, nt2_b, (float*)d_out, NSEL);
  edge_head_kernel<<<(ESEL+15)/16, 256, 0, stream>>>(node, source_index, target_index,
      et1t, et1_b, et2_w, et2_b, (float*)d_out + (size_t)NSEL*3, ESEL);
}